// Round 14
// baseline (346.384 us; speedup 1.0000x reference)
//
#include <hip/hip_runtime.h>
#include <hip/hip_bf16.h>
#include <math.h>

#define NB 4
#define NPTS 4096
#define DIM 256
#define KNN 16
#define HID 64
#define FFDIM 1024
#define LN_EPS 1e-5f
#define MTOT (NB * NPTS)
#define KINF 3e38f
#define QPB 8

typedef __attribute__((ext_vector_type(8))) short short8;
typedef __attribute__((ext_vector_type(4))) float f32x4;

__device__ __forceinline__ float gelu_f(float x) {
    return 0.5f * x * (1.0f + erff(x * 0.7071067811865476f));
}
__device__ __forceinline__ float b2f(ushort u) {
    return __uint_as_float(((unsigned)u) << 16);
}
__device__ __forceinline__ ushort f2b(float f) {
    unsigned u = __float_as_uint(f);
    return (ushort)((u + 0x7fffu + ((u >> 16) & 1u)) >> 16);
}
__device__ __forceinline__ void gload16(const void* g, void* l) {
    __builtin_amdgcn_global_load_lds((const __attribute__((address_space(1))) void*)g,
                                     (__attribute__((address_space(3))) void*)l, 16, 0, 0);
}
// dot of 8 bf16 (packed in uint4) with 8 consecutive f32
__device__ __forceinline__ float dot8(uint4 w, const float* q) {
    float s = 0.f;
    s += b2f((ushort)(w.x & 0xffff)) * q[0]; s += b2f((ushort)(w.x >> 16)) * q[1];
    s += b2f((ushort)(w.y & 0xffff)) * q[2]; s += b2f((ushort)(w.y >> 16)) * q[3];
    s += b2f((ushort)(w.z & 0xffff)) * q[4]; s += b2f((ushort)(w.z >> 16)) * q[5];
    s += b2f((ushort)(w.w & 0xffff)) * q[6]; s += b2f((ushort)(w.w >> 16)) * q[7];
    return s;
}

// ---------------------------------------------------------------------------
// KNN v8 body (validated round 13) as a device function over a shared buffer.
// smem layout: pxS f[4096] @0 | pyS @16K | pzS @32K | cnt int[8] @49152 |
//              cV f[8][64] @49184 | cI int[8][64] @51232   (total 53280 B)
// ---------------------------------------------------------------------------
__device__ __forceinline__ void knn_body(char* smem, int blk,
                                         const float* __restrict__ xyz,
                                         int* __restrict__ idx_out) {
    float* pxS = (float*)smem;
    float* pyS = (float*)(smem + 16384);
    float* pzS = (float*)(smem + 32768);
    int*   cnt = (int*)(smem + 49152);
    float (*cV)[64] = (float(*)[64])(smem + 49184);
    int   (*cI)[64] = (int(*)[64])(smem + 51232);

    int bq0 = blk * QPB;
    int b = bq0 >> 12;
    const float* base = xyz + (size_t)b * NPTS * 3;
    int t = threadIdx.x;
    int lane = t & 63, wv = t >> 6;

    if (t < QPB) cnt[t] = 0;
    for (int i = t; i < NPTS; i += 256) {
        pxS[i] = base[i * 3 + 0];
        pyS[i] = base[i * 3 + 1];
        pzS[i] = base[i * 3 + 2];
    }
    __syncthreads();

    #pragma unroll 1
    for (int rep = 0; rep < 2; ++rep) {
        int qi = wv + 4 * rep;
        int bn = bq0 + qi;
        int n = bn & (NPTS - 1);
        float qx = pxS[n], qy = pyS[n], qz = pzS[n];
        float sqn = qx * qx + qy * qy + qz * qz;

        float d[64];
        float lm = KINF;
        #pragma unroll
        for (int i = 0; i < 64; ++i) {
            int m = lane + 64 * i;
            float x = pxS[m], y = pyS[m], z = pzS[m];
            float sqm = x * x + y * y + z * z;
            float dot = qx * x + qy * y + qz * z;
            float dd = (sqn + sqm) - 2.0f * dot;
            d[i] = (m == n) ? KINF : dd;
            lm = fminf(lm, d[i]);
        }

        float v = lm;
        #pragma unroll
        for (int k = 2; k <= 64; k <<= 1) {
            #pragma unroll
            for (int j = 32; j > 0; j >>= 1) {
                if (j < k) {
                    float ov = __shfl_xor(v, j, 64);
                    bool keepMin = ((lane & k) == 0) == ((lane & j) == 0);
                    if (keepMin == (ov < v)) v = ov;
                }
            }
        }
        float T = __shfl(v, 15, 64);

        #pragma unroll
        for (int i = 0; i < 64; ++i) {
            if (d[i] <= T) {
                int pos = atomicAdd(&cnt[qi], 1);
                if (pos < 64) { cV[qi][pos] = d[i]; cI[qi][pos] = lane + 64 * i; }
            }
        }

        int nc = cnt[qi]; nc = nc > 64 ? 64 : nc;
        float v2 = (lane < nc) ? cV[qi][lane] : KINF;
        int   m2 = (lane < nc) ? cI[qi][lane] : 0x7fffffff;
        #pragma unroll
        for (int k = 2; k <= 64; k <<= 1) {
            #pragma unroll
            for (int j = 32; j > 0; j >>= 1) {
                if (j < k) {
                    float ov = __shfl_xor(v2, j, 64);
                    int   om = __shfl_xor(m2, j, 64);
                    bool keepMin = ((lane & k) == 0) == ((lane & j) == 0);
                    bool less = (ov < v2) || (ov == v2 && om < m2);
                    if (keepMin == less) { v2 = ov; m2 = om; }
                }
            }
        }
        if (lane < KNN) idx_out[(size_t)bn * KNN + lane] = m2;
    }
}

// ---------------------------------------------------------------------------
// GEMM body (validated round 13 gemm_bt, ACT=0/OUTBF=1/RES=0) over smem:
// As @0 (8KB) | Bs @8192 (8KB)
// ---------------------------------------------------------------------------
__device__ __forceinline__ void gemm_body(char* smem, int bx, int by,
                                          const ushort* __restrict__ A,
                                          const ushort* __restrict__ Bt,
                                          const float* __restrict__ bias,
                                          ushort* __restrict__ Cb,
                                          int N, int K, int ldc) {
    ushort* As = (ushort*)smem;
    ushort* Bs = (ushort*)(smem + 8192);
    const int t = threadIdx.x;
    const int wave = t >> 6, lane = t & 63;
    const int m0 = by * 128, n0 = bx * 128;
    const int wr = (wave >> 1) * 64, wc = (wave & 1) * 64;

    f32x4 acc[4][4];
    #pragma unroll
    for (int i = 0; i < 4; ++i)
        #pragma unroll
        for (int j = 0; j < 4; ++j) acc[i][j] = {0.f, 0.f, 0.f, 0.f};

    const int rA0 = (wave * 2 + 0) * 16 + (lane >> 2);
    const int rA1 = (wave * 2 + 1) * 16 + (lane >> 2);
    const int u4 = lane & 3;
    const int sw0 = (rA0 + (rA0 >> 2)) & 3;
    const int sw1 = (rA1 + (rA1 >> 2)) & 3;
    char* ldsA0 = (char*)As + (wave * 2 + 0) * 1024 + lane * 16;
    char* ldsA1 = (char*)As + (wave * 2 + 1) * 1024 + lane * 16;
    char* ldsB0 = (char*)Bs + (wave * 2 + 0) * 1024 + lane * 16;
    char* ldsB1 = (char*)Bs + (wave * 2 + 1) * 1024 + lane * 16;
    const size_t aOff0 = (size_t)(m0 + rA0) * K + (size_t)((u4 ^ sw0) * 8);
    const size_t aOff1 = (size_t)(m0 + rA1) * K + (size_t)((u4 ^ sw1) * 8);
    const size_t bOff0 = (size_t)(n0 + rA0) * K + (size_t)((u4 ^ sw0) * 8);
    const size_t bOff1 = (size_t)(n0 + rA1) * K + (size_t)((u4 ^ sw1) * 8);

    const int cl = lane & 15, gq = lane >> 4;

    for (int k0 = 0; k0 < K; k0 += 32) {
        gload16(A + aOff0 + k0, ldsA0);
        gload16(A + aOff1 + k0, ldsA1);
        gload16(Bt + bOff0 + k0, ldsB0);
        gload16(Bt + bOff1 + k0, ldsB1);
        __syncthreads();

        short8 av[4], bv[4];
        #pragma unroll
        for (int mi = 0; mi < 4; ++mi) {
            int row = wr + mi * 16 + cl;
            int s = (row + (row >> 2)) & 3;
            av[mi] = *(const short8*)((const char*)As + row * 64 + ((gq ^ s) << 4));
            int rowb = wc + mi * 16 + cl;
            int sb = (rowb + (rowb >> 2)) & 3;
            bv[mi] = *(const short8*)((const char*)Bs + rowb * 64 + ((gq ^ sb) << 4));
        }
        #pragma unroll
        for (int mi = 0; mi < 4; ++mi)
            #pragma unroll
            for (int ni = 0; ni < 4; ++ni)
                acc[mi][ni] = __builtin_amdgcn_mfma_f32_16x16x32_bf16(av[mi], bv[ni], acc[mi][ni], 0, 0, 0);
        __syncthreads();
    }

    #pragma unroll
    for (int ni = 0; ni < 4; ++ni) {
        int col = n0 + wc + ni * 16 + cl;
        float bvv = bias[col];
        #pragma unroll
        for (int mi = 0; mi < 4; ++mi) {
            #pragma unroll
            for (int r = 0; r < 4; ++r) {
                int row = m0 + wr + mi * 16 + gq * 4 + r;
                Cb[(size_t)row * ldc + col] = f2b(acc[mi][ni][r] + bvv);
            }
        }
    }
}

// ---------------------------------------------------------------------------
// Merged dispatch: 3072 blocks, 2:1 interleave. bid%3==2 -> qkvw GEMM block
// g=bid/3 (bx=g&7, by=g>>3); else knn block knn_id = bid - bid/3.
// knn and qkvw GEMM are data-independent (xyz->idx vs xb->qkvw); MFMA and
// VALU pipes co-schedule (m114) so the GEMM hides under knn's latency.
// ---------------------------------------------------------------------------
__global__ __launch_bounds__(256) void knn_qkvw_kernel(
    const float* __restrict__ xyz, int* __restrict__ idx_out,
    const ushort* __restrict__ xb, const ushort* __restrict__ BtQKVW,
    const float* __restrict__ bqkvw, ushort* __restrict__ qkvw)
{
    __shared__ char smem[53280];
    int bid = blockIdx.x;
    int g = bid / 3;
    if (bid - g * 3 == 2) {
        gemm_body(smem, g & 7, g >> 3, xb, BtQKVW, bqkvw, qkvw, 1024, 256, 1024);
    } else {
        knn_body(smem, bid - g, xyz, idx_out);
    }
}

// ---------------------------------------------------------------------------
// LayerNorm f32 in -> bf16 out
// ---------------------------------------------------------------------------
__global__ __launch_bounds__(256) void ln_kernel(const float* __restrict__ in,
                                                 const float* __restrict__ g,
                                                 const float* __restrict__ bb,
                                                 ushort* __restrict__ out) {
    int r = blockIdx.x;
    int t = threadIdx.x;
    float v = in[(size_t)r * DIM + t];

    __shared__ float sw[4];
    __shared__ float sw2[4];

    float s = v;
    #pragma unroll
    for (int off = 32; off > 0; off >>= 1) s += __shfl_down(s, off);
    if ((t & 63) == 0) sw[t >> 6] = s;
    __syncthreads();
    float mean = (sw[0] + sw[1] + sw[2] + sw[3]) * (1.0f / DIM);

    float dlt = v - mean;
    float s2 = dlt * dlt;
    #pragma unroll
    for (int off = 32; off > 0; off >>= 1) s2 += __shfl_down(s2, off);
    if ((t & 63) == 0) sw2[t >> 6] = s2;
    __syncthreads();
    float var = (sw2[0] + sw2[1] + sw2[2] + sw2[3]) * (1.0f / DIM);

    out[(size_t)r * DIM + t] = f2b(dlt * rsqrtf(var + LN_EPS) * g[t] + bb[t]);
}

// ---------------------------------------------------------------------------
// Batched transpose-convert (4x 256x256)
// ---------------------------------------------------------------------------
__global__ __launch_bounds__(256) void tconv4(const float* __restrict__ s0,
                                              const float* __restrict__ s1,
                                              const float* __restrict__ s2,
                                              const float* __restrict__ s3,
                                              ushort* __restrict__ d0,
                                              ushort* __restrict__ d1,
                                              ushort* __restrict__ d2,
                                              ushort* __restrict__ d3) {
    const float* in; ushort* out;
    switch (blockIdx.z) {
        case 0: in = s0; out = d0; break;
        case 1: in = s1; out = d1; break;
        case 2: in = s2; out = d2; break;
        default: in = s3; out = d3; break;
    }
    __shared__ float tile[32][33];
    int tx = threadIdx.x & 31, ty = threadIdx.x >> 5;
    int r0 = blockIdx.y * 32, c0 = blockIdx.x * 32;
    #pragma unroll
    for (int k = 0; k < 4; ++k)
        tile[ty + 8 * k][tx] = in[(size_t)(r0 + ty + 8 * k) * 256 + c0 + tx];
    __syncthreads();
    #pragma unroll
    for (int k = 0; k < 4; ++k)
        out[(size_t)(c0 + ty + 8 * k) * 256 + r0 + tx] = f2b(tile[tx][ty + 8 * k]);
}

// generic tconv for FF weights
__global__ __launch_bounds__(256) void tconv(const float* __restrict__ in,
                                             ushort* __restrict__ out, int R, int C) {
    __shared__ float tile[32][33];
    int tx = threadIdx.x & 31, ty = threadIdx.x >> 5;
    int r0 = blockIdx.y * 32, c0 = blockIdx.x * 32;
    #pragma unroll
    for (int k = 0; k < 4; ++k)
        tile[ty + 8 * k][tx] = in[(size_t)(r0 + ty + 8 * k) * C + c0 + tx];
    __syncthreads();
    #pragma unroll
    for (int k = 0; k < 4; ++k)
        out[(size_t)(c0 + ty + 8 * k) * R + r0 + tx] = f2b(tile[tx][ty + 8 * k]);
}

// merged: w2bd rows (0..255) | Wq row-major bf16 (256..511) | catL copy (512..767)
__global__ __launch_bounds__(256) void prep_mats(const float* __restrict__ W2,
                                                 const float* __restrict__ Wq,
                                                 const ushort* __restrict__ WoT,
                                                 ushort* __restrict__ w2bd,
                                                 ushort* __restrict__ Wq_bf,
                                                 ushort* __restrict__ BtCat) {
    int bb = blockIdx.x, t = threadIdx.x;
    if (bb < 256) {
        float v = ((t >> 6) == (bb >> 6)) ? W2[(bb & 63) * 256 + t] : 0.0f;
        w2bd[bb * 256 + t] = f2b(v);
    } else if (bb < 512) {
        int r = bb - 256;
        Wq_bf[r * 256 + t] = f2b(Wq[r * 256 + t]);
    } else {
        int r = bb - 512;
        BtCat[(size_t)r * 512 + t] = WoT[r * 256 + t];
    }
}

// merged biases
__global__ __launch_bounds__(256) void prep_bias(const float* __restrict__ bq,
                                                 const float* __restrict__ bk,
                                                 const float* __restrict__ bv,
                                                 const float* __restrict__ W2,
                                                 const float* __restrict__ bo,
                                                 const float* __restrict__ br2,
                                                 const float* __restrict__ Wo,
                                                 float* __restrict__ bqkvw,
                                                 float* __restrict__ boc) {
    int bb = blockIdx.x, t = threadIdx.x;
    if (bb == 0) bqkvw[t] = bq[t];
    else if (bb == 1) bqkvw[256 + t] = bk[t];
    else if (bb == 2) bqkvw[512 + t] = bv[t];
    else if (bb == 3) {
        int h = t >> 6, i = t & 63;
        float s = 0.f;
        #pragma unroll 8
        for (int dp = 0; dp < 64; ++dp) s += bq[h * 64 + dp] * W2[i * 256 + h * 64 + dp];
        bqkvw[768 + t] = s;
    } else {
        float s = bo[t];
        #pragma unroll 8
        for (int d = 0; d < 256; ++d) s += br2[d] * Wo[d * 256 + t];
        boc[t] = s;
    }
}

// ---------------------------------------------------------------------------
// MFMA bf16 GEMM: C[M][ldc] = act(A[M][K] @ Bt[N][K]^T + bias) (+res)
// ---------------------------------------------------------------------------
template <int ACT, int OUTBF, int RES>
__global__ __launch_bounds__(256) void gemm_bt(
    const ushort* __restrict__ A, const ushort* __restrict__ Bt,
    const float* __restrict__ bias, const float* __restrict__ res,
    void* __restrict__ Cv, int M, int N, int K, int ldc)
{
    __shared__ ushort As[4096];
    __shared__ ushort Bs[4096];
    const int t = threadIdx.x;
    const int wave = t >> 6, lane = t & 63;
    const int m0 = blockIdx.y * 128, n0 = blockIdx.x * 128;
    const int wr = (wave >> 1) * 64, wc = (wave & 1) * 64;

    f32x4 acc[4][4];
    #pragma unroll
    for (int i = 0; i < 4; ++i)
        #pragma unroll
        for (int j = 0; j < 4; ++j) acc[i][j] = {0.f, 0.f, 0.f, 0.f};

    const int rA0 = (wave * 2 + 0) * 16 + (lane >> 2);
    const int rA1 = (wave * 2 + 1) * 16 + (lane >> 2);
    const int u4 = lane & 3;
    const int sw0 = (rA0 + (rA0 >> 2)) & 3;
    const int sw1 = (rA1 + (rA1 >> 2)) & 3;
    char* ldsA0 = (char*)As + (wave * 2 + 0) * 1024 + lane * 16;
    char* ldsA1 = (char*)As + (wave * 2 + 1) * 1024 + lane * 16;
    char* ldsB0 = (char*)Bs + (wave * 2 + 0) * 1024 + lane * 16;
    char* ldsB1 = (char*)Bs + (wave * 2 + 1) * 1024 + lane * 16;
    const size_t aOff0 = (size_t)(m0 + rA0) * K + (size_t)((u4 ^ sw0) * 8);
    const size_t aOff1 = (size_t)(m0 + rA1) * K + (size_t)((u4 ^ sw1) * 8);
    const size_t bOff0 = (size_t)(n0 + rA0) * K + (size_t)((u4 ^ sw0) * 8);
    const size_t bOff1 = (size_t)(n0 + rA1) * K + (size_t)((u4 ^ sw1) * 8);

    const int cl = lane & 15, gq = lane >> 4;

    for (int k0 = 0; k0 < K; k0 += 32) {
        gload16(A + aOff0 + k0, ldsA0);
        gload16(A + aOff1 + k0, ldsA1);
        gload16(Bt + bOff0 + k0, ldsB0);
        gload16(Bt + bOff1 + k0, ldsB1);
        __syncthreads();

        short8 av[4], bv[4];
        #pragma unroll
        for (int mi = 0; mi < 4; ++mi) {
            int row = wr + mi * 16 + cl;
            int s = (row + (row >> 2)) & 3;
            av[mi] = *(const short8*)((const char*)As + row * 64 + ((gq ^ s) << 4));
            int rowb = wc + mi * 16 + cl;
            int sb = (rowb + (rowb >> 2)) & 3;
            bv[mi] = *(const short8*)((const char*)Bs + rowb * 64 + ((gq ^ sb) << 4));
        }
        #pragma unroll
        for (int mi = 0; mi < 4; ++mi)
            #pragma unroll
            for (int ni = 0; ni < 4; ++ni)
                acc[mi][ni] = __builtin_amdgcn_mfma_f32_16x16x32_bf16(av[mi], bv[ni], acc[mi][ni], 0, 0, 0);
        __syncthreads();
    }

    float* Cf = (float*)Cv;
    ushort* Cb = (ushort*)Cv;
    #pragma unroll
    for (int ni = 0; ni < 4; ++ni) {
        int col = n0 + wc + ni * 16 + cl;
        float bvv = bias ? bias[col] : 0.0f;
        #pragma unroll
        for (int mi = 0; mi < 4; ++mi) {
            #pragma unroll
            for (int r = 0; r < 4; ++r) {
                int row = m0 + wr + mi * 16 + gq * 4 + r;
                float v = acc[mi][ni][r] + bvv;
                if (ACT == 1) v = gelu_f(v);
                if (RES) v += res[(size_t)row * N + col];
                if (OUTBF) Cb[(size_t)row * ldc + col] = f2b(v);
                else       Cf[(size_t)row * ldc + col] = v;
            }
        }
    }
}

// ---------------------------------------------------------------------------
// Attention v5 (validated round 12): hid in-kernel, prologue barrier,
// q/k/v/qw from fused qkvw[16384][1024].
// ---------------------------------------------------------------------------
#define PTS 8
__global__ __launch_bounds__(256) void attn_kernel(
    const int* __restrict__ idx,
    const ushort* __restrict__ qkvw,
    const float* __restrict__ xyz,
    const float* __restrict__ W1,
    const float* __restrict__ b1,
    ushort* __restrict__ ab)
{
    __shared__ float qS[256];
    __shared__ float qwS[256];
    __shared__ float psS[64];
    __shared__ uint4 hidS4[16 * 9];   // [16 rows][stride 144B]
    __shared__ int   nbAll[128];
    __shared__ float w1S[256];
    __shared__ float b1S[64];
    ushort* hidS = (ushort*)hidS4;

    const int t = threadIdx.x;
    const int h = t >> 6, lane = t & 63;
    const int bid = blockIdx.x;
    const int blk = ((bid & 7) << 8) | (bid >> 3);   // XCD-contiguous, bijective
    const int bn0 = blk * PTS;
    const int R0 = blk * (PTS * 16);

    if (t < 128) nbAll[t] = idx[R0 + t];
    w1S[t] = W1[t];
    if (t < 64) b1S[t] = b1[t];
    const float* xb3 = xyz + (size_t)(bn0 >> 12) * NPTS * 3;
    __syncthreads();   // nbAll/w1S/b1S read cross-wave below

    for (int pt = 0; pt < PTS; ++pt) {
        const int bn = bn0 + pt;
        const size_t base = (size_t)(bn >> 12) * NPTS;

        qS[t]  = b2f(qkvw[(size_t)bn * 1024 + t]);
        qwS[t] = b2f(qkvw[(size_t)bn * 1024 + 768 + t]);
        // compute hid rows for this point: j = t>>4 (16 rows), 4 dims/thread
        {
            int n = bn & (NPTS - 1);
            float nx = xb3[n * 3 + 0], ny = xb3[n * 3 + 1], nz = xb3[n * 3 + 2];
            int j = t >> 4;
            int i0 = (t & 15) * 4;
            int m = nbAll[pt * 16 + j];
            float dx = xb3[m * 3 + 0] - nx;
            float dy = xb3[m * 3 + 1] - ny;
            float dz = xb3[m * 3 + 2] - nz;
            float nr = sqrtf(dx * dx + dy * dy + dz * dz);
            uint2 hw;
            float a0 = b1S[i0 + 0] + dx * w1S[i0 + 0] + dy * w1S[64 + i0 + 0] + dz * w1S[128 + i0 + 0] + nr * w1S[192 + i0 + 0];
            float a1 = b1S[i0 + 1] + dx * w1S[i0 + 1] + dy * w1S[64 + i0 + 1] + dz * w1S[128 + i0 + 1] + nr * w1S[192 + i0 + 1];
            float a2 = b1S[i0 + 2] + dx * w1S[i0 + 2] + dy * w1S[64 + i0 + 2] + dz * w1S[128 + i0 + 2] + nr * w1S[192 + i0 + 2];
            float a3 = b1S[i0 + 3] + dx * w1S[i0 + 3] + dy * w1S[64 + i0 + 3] + dz * w1S[128 + i0 + 3] + nr * w1S[192 + i0 + 3];
            hw.x = (uint)f2b(gelu_f(a0)) | ((uint)f2b(gelu_f(a1)) << 16);
            hw.y = (uint)f2b(gelu_f(a2)) | ((uint)f2b(gelu_f(a3)) << 16);
            *(uint2*)(hidS + j * 72 + i0) = hw;
        }
        __syncthreads();

        // logits + softmax (wave h = head h; lane = j*4+sub)
        {
            int j = lane >> 2, sub = lane & 3;
            int m = nbAll[pt * 16 + j];
            const ushort* krow = qkvw + (base + m) * 1024 + 256 + h * 64 + sub * 16;
            uint4 ka = *(const uint4*)krow;
            uint4 kc = *(const uint4*)(krow + 8);
            const float* qp = &qS[h * 64 + sub * 16];
            float d1 = dot8(ka, qp) + dot8(kc, qp + 8);
            const ushort* hrow = hidS + j * 72 + sub * 16;
            uint4 ha = *(const uint4*)hrow;
            uint4 hc = *(const uint4*)(hrow + 8);
            const float* qwp = &qwS[h * 64 + sub * 16];
            float d2 = dot8(ha, qwp) + dot8(hc, qwp + 8);
            float pp = d1 + d2;
            pp += __shfl_xor(pp, 1, 64);
            pp += __shfl_xor(pp, 2, 64);
            pp *= 0.125f;
            float mx = pp;
            mx = fmaxf(mx, __shfl_xor(mx, 4, 64));
            mx = fmaxf(mx, __shfl_xor(mx, 8, 64));
            mx = fmaxf(mx, __shfl_xor(mx, 16, 64));
            mx = fmaxf(mx, __shfl_xor(mx, 32, 64));
            float e = expf(pp - mx);
            float ss = e;
            ss += __shfl_xor(ss, 4, 64);
            ss += __shfl_xor(ss, 8, 64);
            ss += __shfl_xor(ss, 16, 64);
            ss += __shfl_xor(ss, 32, 64);
            float pj = e / ss;
            if (sub == 0) psS[h * 16 + j] = pj;
        }
        __syncthreads();

        // partial + hp
        {
            float o = 0.f, hpv = 0.f;
            #pragma unroll
            for (int j = 0; j < 16; ++j) {
                float p = psS[h * 16 + j];
                int m = nbAll[pt * 16 + j];
                o   += p * b2f(qkvw[(base + m) * 1024 + 512 + t]);
                hpv += p * b2f(hidS[j * 72 + lane]);
            }
            ab[(size_t)bn * 512 + t]       = f2b(o);
            ab[(size_t)bn * 512 + 256 + t] = f2b(hpv);
        }
        __syncthreads();
    }
}

// ---------------------------------------------------------------------------
extern "C" void kernel_launch(void* const* d_in, const int* in_sizes, int n_in,
                              void* d_out, int out_size, void* d_ws, size_t ws_size,
                              hipStream_t stream) {
    const float* xyz    = (const float*)d_in[0];
    const float* feats  = (const float*)d_in[1];
    const float* ln_q_g = (const float*)d_in[2];
    const float* ln_q_b = (const float*)d_in[3];
    const float* Wq     = (const float*)d_in[4];
    const float* bq     = (const float*)d_in[5];
    const float* Wk     = (const float*)d_in[6];
    const float* bk     = (const float*)d_in[7];
    const float* Wv     = (const float*)d_in[8];
    const float* bv     = (const float*)d_in[9];
    const float* W_rel1 = (const float*)d_in[10];
    const float* b_rel1 = (const float*)d_in[11];
    const float* W_rel2 = (const float*)d_in[12];
    const float* b_rel2 = (const float*)d_in[13];
    const float* Wo     = (const float*)d_in[14];
    const float* bo     = (const float*)d_in[15];
    const float* ln_f_g = (const float*)d_in[16];
    const float* ln_f_b = (const float*)d_in[17];
    const float* W_ff1  = (const float*)d_in[18];
    const float* b_ff1  = (const float*)d_in[19];
    const float* W_ff2  = (const float*)d_in[20];
    const float* b_ff2  = (const float*)d_in[21];
    (void)in_sizes; (void)n_in; (void)out_size; (void)ws_size;

    char* ws = (char*)d_ws;
    const size_t MB = 1u << 20;
    int*    idx    = (int*)ws;                        // 1 MB
    ushort* xb     = (ushort*)(ws + 1 * MB);          // 8 MB  (LN out; reused as h)
    ushort* qkvw   = (ushort*)(ws + 9 * MB);          // 32 MB [16384][1024]; feats1 overlays
    ushort* ff1b   = (ushort*)(ws + 41 * MB);         // 32 MB (ff1 out)
    ushort* ab     = (ushort*)(ws + 73 * MB);         // 16 MB [16384][512]
    ushort* BtQKVW = (ushort*)(ws + 89 * MB);         // [1024][256] = 512 KB
    ushort* WoT    = BtQKVW + 262144;                 // 128 KB
    ushort* Wf1T   = WoT + 65536;                     // [1024][256] 512 KB
    ushort* Wf2T   = Wf1T + 262144;                   // [256][1024] 512 KB
    ushort* Wq_bf  = Wf2T + 262144;                   // 128 KB
    ushort* w2bd   = Wq_bf + 65536;                   // 128 KB
    ushort* BtCat  = w2bd + 65536;                    // [256][512] 256 KB
    float*  bqkvw  = (float*)(BtCat + 131072);        // 1024 f32
    float*  boc    = bqkvw + 1024;                    // 256 f32
    float*  feats1 = (float*)(ws + 9 * MB);           // overlays qkvw (dead by then)
    ushort* hb     = xb;                              // overlays xb (dead by then)

    // ---- weight preprocessing ----
    tconv4<<<dim3(8, 8, 4), 256, 0, stream>>>(Wq, Wk, Wv, Wo,
                                              BtQKVW, BtQKVW + 65536, BtQKVW + 131072, WoT);
    tconv<<<dim3(32, 8), 256, 0, stream>>>(W_ff1, Wf1T, 256, 1024);
    tconv<<<dim3(8, 32), 256, 0, stream>>>(W_ff2, Wf2T, 1024, 256);
    prep_mats<<<768, 256, 0, stream>>>(W_rel2, Wq, WoT, w2bd, Wq_bf, BtCat);
    gemm_bt<0, 1, 0><<<dim3(2, 2), 256, 0, stream>>>(w2bd, Wq_bf, nullptr, nullptr,
                                                     BtQKVW + 768 * 256, 256, 256, 256, 256);
    gemm_bt<0, 1, 0><<<dim3(2, 2), 256, 0, stream>>>(WoT, w2bd, nullptr, nullptr,
                                                     BtCat + 256, 256, 256, 256, 512);
    prep_bias<<<5, 256, 0, stream>>>(bq, bk, bv, W_rel2, bo, b_rel2, Wo, bqkvw, boc);

    // ---- main pipeline ----
    ln_kernel<<<MTOT, 256, 0, stream>>>(feats, ln_q_g, ln_q_b, xb);

    // merged knn || fused q|k|v|qw GEMM (independent stages, one dispatch)
    knn_qkvw_kernel<<<3072, 256, 0, stream>>>(xyz, idx, xb, BtQKVW, bqkvw, qkvw);

    attn_kernel<<<MTOT / PTS, 256, 0, stream>>>(idx, qkvw, xyz, W_rel1, b_rel1, ab);

    // feats1 = [partial|hp] @ BtCat^T + boc + feats   (overlays qkvw)
    gemm_bt<0, 0, 1><<<dim3(2, 128), 256, 0, stream>>>(ab, BtCat, boc, feats, feats1, MTOT, 256, 512, 256);
    ln_kernel<<<MTOT, 256, 0, stream>>>(feats1, ln_f_g, ln_f_b, hb);
    gemm_bt<1, 1, 0><<<dim3(8, 128), 256, 0, stream>>>(hb, Wf1T, b_ff1, nullptr, ff1b, MTOT, 1024, 256, 1024);
    gemm_bt<0, 0, 1><<<dim3(2, 128), 256, 0, stream>>>(ff1b, Wf2T, b_ff2, feats1, (float*)d_out, MTOT, 256, 1024, 256);
}

// Round 15
// 336.606 us; speedup vs baseline: 1.0290x; 1.0290x over previous
//
#include <hip/hip_runtime.h>
#include <hip/hip_bf16.h>
#include <math.h>

#define NB 4
#define NPTS 4096
#define DIM 256
#define KNN 16
#define HID 64
#define FFDIM 1024
#define LN_EPS 1e-5f
#define MTOT (NB * NPTS)
#define KINF 3e38f
#define QPB 8

typedef __attribute__((ext_vector_type(8))) short short8;
typedef __attribute__((ext_vector_type(4))) float f32x4;

__device__ __forceinline__ float gelu_f(float x) {
    return 0.5f * x * (1.0f + erff(x * 0.7071067811865476f));
}
__device__ __forceinline__ float b2f(ushort u) {
    return __uint_as_float(((unsigned)u) << 16);
}
__device__ __forceinline__ ushort f2b(float f) {
    unsigned u = __float_as_uint(f);
    return (ushort)((u + 0x7fffu + ((u >> 16) & 1u)) >> 16);
}
__device__ __forceinline__ void gload16(const void* g, void* l) {
    __builtin_amdgcn_global_load_lds((const __attribute__((address_space(1))) void*)g,
                                     (__attribute__((address_space(3))) void*)l, 16, 0, 0);
}
// dot of 8 bf16 (packed in uint4) with 8 consecutive f32
__device__ __forceinline__ float dot8(uint4 w, const float* q) {
    float s = 0.f;
    s += b2f((ushort)(w.x & 0xffff)) * q[0]; s += b2f((ushort)(w.x >> 16)) * q[1];
    s += b2f((ushort)(w.y & 0xffff)) * q[2]; s += b2f((ushort)(w.y >> 16)) * q[3];
    s += b2f((ushort)(w.z & 0xffff)) * q[4]; s += b2f((ushort)(w.z >> 16)) * q[5];
    s += b2f((ushort)(w.w & 0xffff)) * q[6]; s += b2f((ushort)(w.w >> 16)) * q[7];
    return s;
}

// ---------------------------------------------------------------------------
// KNN v8b: wave-autonomous (round-13 algorithm, bit-identical selection), but
// xyz read straight from global (48KB batch is L1/L2-resident) instead of LDS
// staging — round-13 counters showed the 53.7KB LDS capped occupancy at 20%
// (2 blocks/CU), leaving the serial shfl chains unhidden. LDS now 4.6KB ->
// ~4 blocks/CU. Wave w owns queries w and w+4: 64 distances/lane in regs ->
// lane-min -> wave sort-64 -> T = rank-15 -> compact (wave-private) ->
// wave lexicographic sort-64 -> write.
// ---------------------------------------------------------------------------
__global__ __launch_bounds__(256) void knn_kernel(const float* __restrict__ xyz,
                                                  int* __restrict__ idx_out) {
    int blk = blockIdx.x;              // MTOT/QPB = 2048
    int bq0 = blk * QPB;
    int b = bq0 >> 12;
    const float* base = xyz + (size_t)b * NPTS * 3;
    int t = threadIdx.x;
    int lane = t & 63, wv = t >> 6;

    __shared__ int   cnt[QPB];
    __shared__ float cV[QPB][64];
    __shared__ int   cI[QPB][64];

    if (t < QPB) cnt[t] = 0;
    __syncthreads();                   // the only barrier (cnt visibility)

    #pragma unroll 1
    for (int rep = 0; rep < 2; ++rep) {
        int qi = wv + 4 * rep;         // wave-private query slot
        int bn = bq0 + qi;
        int n = bn & (NPTS - 1);
        float qx = base[n * 3 + 0], qy = base[n * 3 + 1], qz = base[n * 3 + 2];
        float sqn = qx * qx + qy * qy + qz * qz;

        float d[64];
        float lm = KINF;
        #pragma unroll
        for (int i = 0; i < 64; ++i) {
            int m = lane + 64 * i;
            float x = base[m * 3 + 0], y = base[m * 3 + 1], z = base[m * 3 + 2];
            float sqm = x * x + y * y + z * z;
            float dot = qx * x + qy * y + qz * z;
            float dd = (sqn + sqm) - 2.0f * dot;
            d[i] = (m == n) ? KINF : dd;
            lm = fminf(lm, d[i]);
        }

        // wave ascending bitonic sort of the 64 lane-mins
        float v = lm;
        #pragma unroll
        for (int k = 2; k <= 64; k <<= 1) {
            #pragma unroll
            for (int j = 32; j > 0; j >>= 1) {
                if (j < k) {
                    float ov = __shfl_xor(v, j, 64);
                    bool keepMin = ((lane & k) == 0) == ((lane & j) == 0);
                    if (keepMin == (ov < v)) v = ov;
                }
            }
        }
        float T = __shfl(v, 15, 64);   // 16th-smallest lane-min

        // compact candidates from stored registers (wave-private cnt)
        #pragma unroll
        for (int i = 0; i < 64; ++i) {
            if (d[i] <= T) {
                int pos = atomicAdd(&cnt[qi], 1);
                if (pos < 64) { cV[qi][pos] = d[i]; cI[qi][pos] = lane + 64 * i; }
            }
        }

        // wave-local lexicographic (d, idx) sort of up to 64 candidates
        int nc = cnt[qi]; nc = nc > 64 ? 64 : nc;
        float v2 = (lane < nc) ? cV[qi][lane] : KINF;
        int   m2 = (lane < nc) ? cI[qi][lane] : 0x7fffffff;
        #pragma unroll
        for (int k = 2; k <= 64; k <<= 1) {
            #pragma unroll
            for (int j = 32; j > 0; j >>= 1) {
                if (j < k) {
                    float ov = __shfl_xor(v2, j, 64);
                    int   om = __shfl_xor(m2, j, 64);
                    bool keepMin = ((lane & k) == 0) == ((lane & j) == 0);
                    bool less = (ov < v2) || (ov == v2 && om < m2);
                    if (keepMin == less) { v2 = ov; m2 = om; }
                }
            }
        }
        if (lane < KNN) idx_out[(size_t)bn * KNN + lane] = m2;
    }
}

// ---------------------------------------------------------------------------
// LayerNorm f32 in -> bf16 out
// ---------------------------------------------------------------------------
__global__ __launch_bounds__(256) void ln_kernel(const float* __restrict__ in,
                                                 const float* __restrict__ g,
                                                 const float* __restrict__ bb,
                                                 ushort* __restrict__ out) {
    int r = blockIdx.x;
    int t = threadIdx.x;
    float v = in[(size_t)r * DIM + t];

    __shared__ float sw[4];
    __shared__ float sw2[4];

    float s = v;
    #pragma unroll
    for (int off = 32; off > 0; off >>= 1) s += __shfl_down(s, off);
    if ((t & 63) == 0) sw[t >> 6] = s;
    __syncthreads();
    float mean = (sw[0] + sw[1] + sw[2] + sw[3]) * (1.0f / DIM);

    float dlt = v - mean;
    float s2 = dlt * dlt;
    #pragma unroll
    for (int off = 32; off > 0; off >>= 1) s2 += __shfl_down(s2, off);
    if ((t & 63) == 0) sw2[t >> 6] = s2;
    __syncthreads();
    float var = (sw2[0] + sw2[1] + sw2[2] + sw2[3]) * (1.0f / DIM);

    out[(size_t)r * DIM + t] = f2b(dlt * rsqrtf(var + LN_EPS) * g[t] + bb[t]);
}

// ---------------------------------------------------------------------------
// Batched transpose-convert (4x 256x256)
// ---------------------------------------------------------------------------
__global__ __launch_bounds__(256) void tconv4(const float* __restrict__ s0,
                                              const float* __restrict__ s1,
                                              const float* __restrict__ s2,
                                              const float* __restrict__ s3,
                                              ushort* __restrict__ d0,
                                              ushort* __restrict__ d1,
                                              ushort* __restrict__ d2,
                                              ushort* __restrict__ d3) {
    const float* in; ushort* out;
    switch (blockIdx.z) {
        case 0: in = s0; out = d0; break;
        case 1: in = s1; out = d1; break;
        case 2: in = s2; out = d2; break;
        default: in = s3; out = d3; break;
    }
    __shared__ float tile[32][33];
    int tx = threadIdx.x & 31, ty = threadIdx.x >> 5;
    int r0 = blockIdx.y * 32, c0 = blockIdx.x * 32;
    #pragma unroll
    for (int k = 0; k < 4; ++k)
        tile[ty + 8 * k][tx] = in[(size_t)(r0 + ty + 8 * k) * 256 + c0 + tx];
    __syncthreads();
    #pragma unroll
    for (int k = 0; k < 4; ++k)
        out[(size_t)(c0 + ty + 8 * k) * 256 + r0 + tx] = f2b(tile[tx][ty + 8 * k]);
}

// generic tconv for FF weights
__global__ __launch_bounds__(256) void tconv(const float* __restrict__ in,
                                             ushort* __restrict__ out, int R, int C) {
    __shared__ float tile[32][33];
    int tx = threadIdx.x & 31, ty = threadIdx.x >> 5;
    int r0 = blockIdx.y * 32, c0 = blockIdx.x * 32;
    #pragma unroll
    for (int k = 0; k < 4; ++k)
        tile[ty + 8 * k][tx] = in[(size_t)(r0 + ty + 8 * k) * C + c0 + tx];
    __syncthreads();
    #pragma unroll
    for (int k = 0; k < 4; ++k)
        out[(size_t)(c0 + ty + 8 * k) * R + r0 + tx] = f2b(tile[tx][ty + 8 * k]);
}

// merged: w2bd rows (0..255) | Wq row-major bf16 (256..511) | catL copy (512..767)
__global__ __launch_bounds__(256) void prep_mats(const float* __restrict__ W2,
                                                 const float* __restrict__ Wq,
                                                 const ushort* __restrict__ WoT,
                                                 ushort* __restrict__ w2bd,
                                                 ushort* __restrict__ Wq_bf,
                                                 ushort* __restrict__ BtCat) {
    int bb = blockIdx.x, t = threadIdx.x;
    if (bb < 256) {
        float v = ((t >> 6) == (bb >> 6)) ? W2[(bb & 63) * 256 + t] : 0.0f;
        w2bd[bb * 256 + t] = f2b(v);
    } else if (bb < 512) {
        int r = bb - 256;
        Wq_bf[r * 256 + t] = f2b(Wq[r * 256 + t]);
    } else {
        int r = bb - 512;
        BtCat[(size_t)r * 512 + t] = WoT[r * 256 + t];
    }
}

// merged biases
__global__ __launch_bounds__(256) void prep_bias(const float* __restrict__ bq,
                                                 const float* __restrict__ bk,
                                                 const float* __restrict__ bv,
                                                 const float* __restrict__ W2,
                                                 const float* __restrict__ bo,
                                                 const float* __restrict__ br2,
                                                 const float* __restrict__ Wo,
                                                 float* __restrict__ bqkvw,
                                                 float* __restrict__ boc) {
    int bb = blockIdx.x, t = threadIdx.x;
    if (bb == 0) bqkvw[t] = bq[t];
    else if (bb == 1) bqkvw[256 + t] = bk[t];
    else if (bb == 2) bqkvw[512 + t] = bv[t];
    else if (bb == 3) {
        int h = t >> 6, i = t & 63;
        float s = 0.f;
        #pragma unroll 8
        for (int dp = 0; dp < 64; ++dp) s += bq[h * 64 + dp] * W2[i * 256 + h * 64 + dp];
        bqkvw[768 + t] = s;
    } else {
        float s = bo[t];
        #pragma unroll 8
        for (int d = 0; d < 256; ++d) s += br2[d] * Wo[d * 256 + t];
        boc[t] = s;
    }
}

// ---------------------------------------------------------------------------
// MFMA bf16 GEMM: C[M][ldc] = act(A[M][K] @ Bt[N][K]^T + bias) (+res)
// ---------------------------------------------------------------------------
template <int ACT, int OUTBF, int RES>
__global__ __launch_bounds__(256) void gemm_bt(
    const ushort* __restrict__ A, const ushort* __restrict__ Bt,
    const float* __restrict__ bias, const float* __restrict__ res,
    void* __restrict__ Cv, int M, int N, int K, int ldc)
{
    __shared__ ushort As[4096];
    __shared__ ushort Bs[4096];
    const int t = threadIdx.x;
    const int wave = t >> 6, lane = t & 63;
    const int m0 = blockIdx.y * 128, n0 = blockIdx.x * 128;
    const int wr = (wave >> 1) * 64, wc = (wave & 1) * 64;

    f32x4 acc[4][4];
    #pragma unroll
    for (int i = 0; i < 4; ++i)
        #pragma unroll
        for (int j = 0; j < 4; ++j) acc[i][j] = {0.f, 0.f, 0.f, 0.f};

    const int rA0 = (wave * 2 + 0) * 16 + (lane >> 2);
    const int rA1 = (wave * 2 + 1) * 16 + (lane >> 2);
    const int u4 = lane & 3;
    const int sw0 = (rA0 + (rA0 >> 2)) & 3;
    const int sw1 = (rA1 + (rA1 >> 2)) & 3;
    char* ldsA0 = (char*)As + (wave * 2 + 0) * 1024 + lane * 16;
    char* ldsA1 = (char*)As + (wave * 2 + 1) * 1024 + lane * 16;
    char* ldsB0 = (char*)Bs + (wave * 2 + 0) * 1024 + lane * 16;
    char* ldsB1 = (char*)Bs + (wave * 2 + 1) * 1024 + lane * 16;
    const size_t aOff0 = (size_t)(m0 + rA0) * K + (size_t)((u4 ^ sw0) * 8);
    const size_t aOff1 = (size_t)(m0 + rA1) * K + (size_t)((u4 ^ sw1) * 8);
    const size_t bOff0 = (size_t)(n0 + rA0) * K + (size_t)((u4 ^ sw0) * 8);
    const size_t bOff1 = (size_t)(n0 + rA1) * K + (size_t)((u4 ^ sw1) * 8);

    const int cl = lane & 15, gq = lane >> 4;

    for (int k0 = 0; k0 < K; k0 += 32) {
        gload16(A + aOff0 + k0, ldsA0);
        gload16(A + aOff1 + k0, ldsA1);
        gload16(Bt + bOff0 + k0, ldsB0);
        gload16(Bt + bOff1 + k0, ldsB1);
        __syncthreads();

        short8 av[4], bv[4];
        #pragma unroll
        for (int mi = 0; mi < 4; ++mi) {
            int row = wr + mi * 16 + cl;
            int s = (row + (row >> 2)) & 3;
            av[mi] = *(const short8*)((const char*)As + row * 64 + ((gq ^ s) << 4));
            int rowb = wc + mi * 16 + cl;
            int sb = (rowb + (rowb >> 2)) & 3;
            bv[mi] = *(const short8*)((const char*)Bs + rowb * 64 + ((gq ^ sb) << 4));
        }
        #pragma unroll
        for (int mi = 0; mi < 4; ++mi)
            #pragma unroll
            for (int ni = 0; ni < 4; ++ni)
                acc[mi][ni] = __builtin_amdgcn_mfma_f32_16x16x32_bf16(av[mi], bv[ni], acc[mi][ni], 0, 0, 0);
        __syncthreads();
    }

    float* Cf = (float*)Cv;
    ushort* Cb = (ushort*)Cv;
    #pragma unroll
    for (int ni = 0; ni < 4; ++ni) {
        int col = n0 + wc + ni * 16 + cl;
        float bvv = bias ? bias[col] : 0.0f;
        #pragma unroll
        for (int mi = 0; mi < 4; ++mi) {
            #pragma unroll
            for (int r = 0; r < 4; ++r) {
                int row = m0 + wr + mi * 16 + gq * 4 + r;
                float v = acc[mi][ni][r] + bvv;
                if (ACT == 1) v = gelu_f(v);
                if (RES) v += res[(size_t)row * N + col];
                if (OUTBF) Cb[(size_t)row * ldc + col] = f2b(v);
                else       Cf[(size_t)row * ldc + col] = v;
            }
        }
    }
}

// ---------------------------------------------------------------------------
// Attention v5 (validated round 12): hid in-kernel, prologue barrier,
// q/k/v/qw from fused qkvw[16384][1024].
// ---------------------------------------------------------------------------
#define PTS 8
__global__ __launch_bounds__(256) void attn_kernel(
    const int* __restrict__ idx,
    const ushort* __restrict__ qkvw,
    const float* __restrict__ xyz,
    const float* __restrict__ W1,
    const float* __restrict__ b1,
    ushort* __restrict__ ab)
{
    __shared__ float qS[256];
    __shared__ float qwS[256];
    __shared__ float psS[64];
    __shared__ uint4 hidS4[16 * 9];   // [16 rows][stride 144B]
    __shared__ int   nbAll[128];
    __shared__ float w1S[256];
    __shared__ float b1S[64];
    ushort* hidS = (ushort*)hidS4;

    const int t = threadIdx.x;
    const int h = t >> 6, lane = t & 63;
    const int bid = blockIdx.x;
    const int blk = ((bid & 7) << 8) | (bid >> 3);   // XCD-contiguous, bijective
    const int bn0 = blk * PTS;
    const int R0 = blk * (PTS * 16);

    if (t < 128) nbAll[t] = idx[R0 + t];
    w1S[t] = W1[t];
    if (t < 64) b1S[t] = b1[t];
    const float* xb3 = xyz + (size_t)(bn0 >> 12) * NPTS * 3;
    __syncthreads();   // nbAll/w1S/b1S read cross-wave below

    for (int pt = 0; pt < PTS; ++pt) {
        const int bn = bn0 + pt;
        const size_t base = (size_t)(bn >> 12) * NPTS;

        qS[t]  = b2f(qkvw[(size_t)bn * 1024 + t]);
        qwS[t] = b2f(qkvw[(size_t)bn * 1024 + 768 + t]);
        // compute hid rows for this point: j = t>>4 (16 rows), 4 dims/thread
        {
            int n = bn & (NPTS - 1);
            float nx = xb3[n * 3 + 0], ny = xb3[n * 3 + 1], nz = xb3[n * 3 + 2];
            int j = t >> 4;
            int i0 = (t & 15) * 4;
            int m = nbAll[pt * 16 + j];
            float dx = xb3[m * 3 + 0] - nx;
            float dy = xb3[m * 3 + 1] - ny;
            float dz = xb3[m * 3 + 2] - nz;
            float nr = sqrtf(dx * dx + dy * dy + dz * dz);
            uint2 hw;
            float a0 = b1S[i0 + 0] + dx * w1S[i0 + 0] + dy * w1S[64 + i0 + 0] + dz * w1S[128 + i0 + 0] + nr * w1S[192 + i0 + 0];
            float a1 = b1S[i0 + 1] + dx * w1S[i0 + 1] + dy * w1S[64 + i0 + 1] + dz * w1S[128 + i0 + 1] + nr * w1S[192 + i0 + 1];
            float a2 = b1S[i0 + 2] + dx * w1S[i0 + 2] + dy * w1S[64 + i0 + 2] + dz * w1S[128 + i0 + 2] + nr * w1S[192 + i0 + 2];
            float a3 = b1S[i0 + 3] + dx * w1S[i0 + 3] + dy * w1S[64 + i0 + 3] + dz * w1S[128 + i0 + 3] + nr * w1S[192 + i0 + 3];
            hw.x = (uint)f2b(gelu_f(a0)) | ((uint)f2b(gelu_f(a1)) << 16);
            hw.y = (uint)f2b(gelu_f(a2)) | ((uint)f2b(gelu_f(a3)) << 16);
            *(uint2*)(hidS + j * 72 + i0) = hw;
        }
        __syncthreads();

        // logits + softmax (wave h = head h; lane = j*4+sub)
        {
            int j = lane >> 2, sub = lane & 3;
            int m = nbAll[pt * 16 + j];
            const ushort* krow = qkvw + (base + m) * 1024 + 256 + h * 64 + sub * 16;
            uint4 ka = *(const uint4*)krow;
            uint4 kc = *(const uint4*)(krow + 8);
            const float* qp = &qS[h * 64 + sub * 16];
            float d1 = dot8(ka, qp) + dot8(kc, qp + 8);
            const ushort* hrow = hidS + j * 72 + sub * 16;
            uint4 ha = *(const uint4*)hrow;
            uint4 hc = *(const uint4*)(hrow + 8);
            const float* qwp = &qwS[h * 64 + sub * 16];
            float d2 = dot8(ha, qwp) + dot8(hc, qwp + 8);
            float pp = d1 + d2;
            pp += __shfl_xor(pp, 1, 64);
            pp += __shfl_xor(pp, 2, 64);
            pp *= 0.125f;
            float mx = pp;
            mx = fmaxf(mx, __shfl_xor(mx, 4, 64));
            mx = fmaxf(mx, __shfl_xor(mx, 8, 64));
            mx = fmaxf(mx, __shfl_xor(mx, 16, 64));
            mx = fmaxf(mx, __shfl_xor(mx, 32, 64));
            float e = expf(pp - mx);
            float ss = e;
            ss += __shfl_xor(ss, 4, 64);
            ss += __shfl_xor(ss, 8, 64);
            ss += __shfl_xor(ss, 16, 64);
            ss += __shfl_xor(ss, 32, 64);
            float pj = e / ss;
            if (sub == 0) psS[h * 16 + j] = pj;
        }
        __syncthreads();

        // partial + hp
        {
            float o = 0.f, hpv = 0.f;
            #pragma unroll
            for (int j = 0; j < 16; ++j) {
                float p = psS[h * 16 + j];
                int m = nbAll[pt * 16 + j];
                o   += p * b2f(qkvw[(base + m) * 1024 + 512 + t]);
                hpv += p * b2f(hidS[j * 72 + lane]);
            }
            ab[(size_t)bn * 512 + t]       = f2b(o);
            ab[(size_t)bn * 512 + 256 + t] = f2b(hpv);
        }
        __syncthreads();
    }
}

// ---------------------------------------------------------------------------
extern "C" void kernel_launch(void* const* d_in, const int* in_sizes, int n_in,
                              void* d_out, int out_size, void* d_ws, size_t ws_size,
                              hipStream_t stream) {
    const float* xyz    = (const float*)d_in[0];
    const float* feats  = (const float*)d_in[1];
    const float* ln_q_g = (const float*)d_in[2];
    const float* ln_q_b = (const float*)d_in[3];
    const float* Wq     = (const float*)d_in[4];
    const float* bq     = (const float*)d_in[5];
    const float* Wk     = (const float*)d_in[6];
    const float* bk     = (const float*)d_in[7];
    const float* Wv     = (const float*)d_in[8];
    const float* bv     = (const float*)d_in[9];
    const float* W_rel1 = (const float*)d_in[10];
    const float* b_rel1 = (const float*)d_in[11];
    const float* W_rel2 = (const float*)d_in[12];
    const float* b_rel2 = (const float*)d_in[13];
    const float* Wo     = (const float*)d_in[14];
    const float* bo     = (const float*)d_in[15];
    const float* ln_f_g = (const float*)d_in[16];
    const float* ln_f_b = (const float*)d_in[17];
    const float* W_ff1  = (const float*)d_in[18];
    const float* b_ff1  = (const float*)d_in[19];
    const float* W_ff2  = (const float*)d_in[20];
    const float* b_ff2  = (const float*)d_in[21];
    (void)in_sizes; (void)n_in; (void)out_size; (void)ws_size;

    char* ws = (char*)d_ws;
    const size_t MB = 1u << 20;
    int*    idx    = (int*)ws;                        // 1 MB
    ushort* xb     = (ushort*)(ws + 1 * MB);          // 8 MB  (LN out; reused as h)
    ushort* qkvw   = (ushort*)(ws + 9 * MB);          // 32 MB [16384][1024]; feats1 overlays
    ushort* ff1b   = (ushort*)(ws + 41 * MB);         // 32 MB (ff1 out)
    ushort* ab     = (ushort*)(ws + 73 * MB);         // 16 MB [16384][512]
    ushort* BtQKVW = (ushort*)(ws + 89 * MB);         // [1024][256] = 512 KB
    ushort* WoT    = BtQKVW + 262144;                 // 128 KB
    ushort* Wf1T   = WoT + 65536;                     // [1024][256] 512 KB
    ushort* Wf2T   = Wf1T + 262144;                   // [256][1024] 512 KB
    ushort* Wq_bf  = Wf2T + 262144;                   // 128 KB
    ushort* w2bd   = Wq_bf + 65536;                   // 128 KB
    ushort* BtCat  = w2bd + 65536;                    // [256][512] 256 KB
    float*  bqkvw  = (float*)(BtCat + 131072);        // 1024 f32
    float*  boc    = bqkvw + 1024;                    // 256 f32
    float*  feats1 = (float*)(ws + 9 * MB);           // overlays qkvw (dead by then)
    ushort* hb     = xb;                              // overlays xb (dead by then)

    // ---- weight preprocessing ----
    tconv4<<<dim3(8, 8, 4), 256, 0, stream>>>(Wq, Wk, Wv, Wo,
                                              BtQKVW, BtQKVW + 65536, BtQKVW + 131072, WoT);
    tconv<<<dim3(32, 8), 256, 0, stream>>>(W_ff1, Wf1T, 256, 1024);
    tconv<<<dim3(8, 32), 256, 0, stream>>>(W_ff2, Wf2T, 1024, 256);
    prep_mats<<<768, 256, 0, stream>>>(W_rel2, Wq, WoT, w2bd, Wq_bf, BtCat);
    gemm_bt<0, 1, 0><<<dim3(2, 2), 256, 0, stream>>>(w2bd, Wq_bf, nullptr, nullptr,
                                                     BtQKVW + 768 * 256, 256, 256, 256, 256);
    gemm_bt<0, 1, 0><<<dim3(2, 2), 256, 0, stream>>>(WoT, w2bd, nullptr, nullptr,
                                                     BtCat + 256, 256, 256, 256, 512);
    prep_bias<<<5, 256, 0, stream>>>(bq, bk, bv, W_rel2, bo, b_rel2, Wo, bqkvw, boc);

    // ---- main pipeline ----
    knn_kernel<<<MTOT / QPB, 256, 0, stream>>>(xyz, idx);
    ln_kernel<<<MTOT, 256, 0, stream>>>(feats, ln_q_g, ln_q_b, xb);

    // fused q|k|v|qw GEMM: [16384][1024]
    gemm_bt<0, 1, 0><<<dim3(8, 128), 256, 0, stream>>>(xb, BtQKVW, bqkvw, nullptr,
                                                       qkvw, MTOT, 1024, 256, 1024);

    attn_kernel<<<MTOT / PTS, 256, 0, stream>>>(idx, qkvw, xyz, W_rel1, b_rel1, ab);

    // feats1 = [partial|hp] @ BtCat^T + boc + feats   (overlays qkvw)
    gemm_bt<0, 0, 1><<<dim3(2, 128), 256, 0, stream>>>(ab, BtCat, boc, feats, feats1, MTOT, 256, 512, 256);
    ln_kernel<<<MTOT, 256, 0, stream>>>(feats1, ln_f_g, ln_f_b, hb);
    gemm_bt<1, 1, 0><<<dim3(8, 128), 256, 0, stream>>>(hb, Wf1T, b_ff1, nullptr, ff1b, MTOT, 1024, 256, 1024);
    gemm_bt<0, 0, 1><<<dim3(2, 128), 256, 0, stream>>>(ff1b, Wf2T, b_ff2, feats1, (float*)d_out, MTOT, 256, 1024, 256);
}

// Round 16
// 270.054 us; speedup vs baseline: 1.2826x; 1.2464x over previous
//
#include <hip/hip_runtime.h>
#include <hip/hip_bf16.h>
#include <math.h>

#define NB 4
#define NPTS 4096
#define DIM 256
#define KNN 16
#define HID 64
#define FFDIM 1024
#define LN_EPS 1e-5f
#define MTOT (NB * NPTS)
#define KINF 3e38f
#define QPB 8

typedef __attribute__((ext_vector_type(8))) short short8;
typedef __attribute__((ext_vector_type(4))) float f32x4;

__device__ __forceinline__ float gelu_f(float x) {
    return 0.5f * x * (1.0f + erff(x * 0.7071067811865476f));
}
__device__ __forceinline__ float b2f(ushort u) {
    return __uint_as_float(((unsigned)u) << 16);
}
__device__ __forceinline__ ushort f2b(float f) {
    unsigned u = __float_as_uint(f);
    return (ushort)((u + 0x7fffu + ((u >> 16) & 1u)) >> 16);
}
__device__ __forceinline__ void gload16(const void* g, void* l) {
    __builtin_amdgcn_global_load_lds((const __attribute__((address_space(1))) void*)g,
                                     (__attribute__((address_space(3))) void*)l, 16, 0, 0);
}
// dot of 8 bf16 (packed in uint4) with 8 consecutive f32
__device__ __forceinline__ float dot8(uint4 w, const float* q) {
    float s = 0.f;
    s += b2f((ushort)(w.x & 0xffff)) * q[0]; s += b2f((ushort)(w.x >> 16)) * q[1];
    s += b2f((ushort)(w.y & 0xffff)) * q[2]; s += b2f((ushort)(w.y >> 16)) * q[3];
    s += b2f((ushort)(w.z & 0xffff)) * q[4]; s += b2f((ushort)(w.z >> 16)) * q[5];
    s += b2f((ushort)(w.w & 0xffff)) * q[6]; s += b2f((ushort)(w.w >> 16)) * q[7];
    return s;
}

// ---------------------------------------------------------------------------
// KNN v8 (round-13 validated, 68us — FROZEN; v8b global-read variant regressed
// to 122us via VGPR 208 / occupancy 11%). xyz staged in LDS once (1 barrier);
// wave w owns queries w and w+4 end-to-end.
// ---------------------------------------------------------------------------
__global__ __launch_bounds__(256) void knn_kernel(const float* __restrict__ xyz,
                                                  int* __restrict__ idx_out) {
    int blk = blockIdx.x;              // MTOT/QPB = 2048
    int bq0 = blk * QPB;
    int b = bq0 >> 12;
    const float* base = xyz + (size_t)b * NPTS * 3;
    int t = threadIdx.x;
    int lane = t & 63, wv = t >> 6;

    __shared__ float pxS[NPTS];        // 16 KB
    __shared__ float pyS[NPTS];
    __shared__ float pzS[NPTS];
    __shared__ int   cnt[QPB];
    __shared__ float cV[QPB][64];
    __shared__ int   cI[QPB][64];

    if (t < QPB) cnt[t] = 0;
    for (int i = t; i < NPTS; i += 256) {
        pxS[i] = base[i * 3 + 0];
        pyS[i] = base[i * 3 + 1];
        pzS[i] = base[i * 3 + 2];
    }
    __syncthreads();                   // the only barrier

    #pragma unroll 1
    for (int rep = 0; rep < 2; ++rep) {
        int qi = wv + 4 * rep;         // wave-private query slot
        int bn = bq0 + qi;
        int n = bn & (NPTS - 1);
        float qx = pxS[n], qy = pyS[n], qz = pzS[n];
        float sqn = qx * qx + qy * qy + qz * qz;

        float d[64];
        float lm = KINF;
        #pragma unroll
        for (int i = 0; i < 64; ++i) {
            int m = lane + 64 * i;
            float x = pxS[m], y = pyS[m], z = pzS[m];
            float sqm = x * x + y * y + z * z;
            float dot = qx * x + qy * y + qz * z;
            float dd = (sqn + sqm) - 2.0f * dot;
            d[i] = (m == n) ? KINF : dd;
            lm = fminf(lm, d[i]);
        }

        // wave ascending bitonic sort of the 64 lane-mins
        float v = lm;
        #pragma unroll
        for (int k = 2; k <= 64; k <<= 1) {
            #pragma unroll
            for (int j = 32; j > 0; j >>= 1) {
                if (j < k) {
                    float ov = __shfl_xor(v, j, 64);
                    bool keepMin = ((lane & k) == 0) == ((lane & j) == 0);
                    if (keepMin == (ov < v)) v = ov;
                }
            }
        }
        float T = __shfl(v, 15, 64);   // 16th-smallest lane-min

        // compact candidates from stored registers (wave-private cnt)
        #pragma unroll
        for (int i = 0; i < 64; ++i) {
            if (d[i] <= T) {
                int pos = atomicAdd(&cnt[qi], 1);
                if (pos < 64) { cV[qi][pos] = d[i]; cI[qi][pos] = lane + 64 * i; }
            }
        }

        // wave-local lexicographic (d, idx) sort of up to 64 candidates
        int nc = cnt[qi]; nc = nc > 64 ? 64 : nc;
        float v2 = (lane < nc) ? cV[qi][lane] : KINF;
        int   m2 = (lane < nc) ? cI[qi][lane] : 0x7fffffff;
        #pragma unroll
        for (int k = 2; k <= 64; k <<= 1) {
            #pragma unroll
            for (int j = 32; j > 0; j >>= 1) {
                if (j < k) {
                    float ov = __shfl_xor(v2, j, 64);
                    int   om = __shfl_xor(m2, j, 64);
                    bool keepMin = ((lane & k) == 0) == ((lane & j) == 0);
                    bool less = (ov < v2) || (ov == v2 && om < m2);
                    if (keepMin == less) { v2 = ov; m2 = om; }
                }
            }
        }
        if (lane < KNN) idx_out[(size_t)bn * KNN + lane] = m2;
    }
}

// ---------------------------------------------------------------------------
// LayerNorm v2: one wave per row (4 rows/block), float4 loads, shfl_xor
// butterfly reductions (no LDS, no barriers), packed bf16x4 store.
// ---------------------------------------------------------------------------
__global__ __launch_bounds__(256) void ln_kernel(const float* __restrict__ in,
                                                 const float* __restrict__ g,
                                                 const float* __restrict__ bb,
                                                 ushort* __restrict__ out) {
    int lane = threadIdx.x & 63, wv = threadIdx.x >> 6;
    int r = blockIdx.x * 4 + wv;
    const float* row = in + (size_t)r * DIM;

    float4 v = *(const float4*)(row + lane * 4);
    float s = v.x + v.y + v.z + v.w;
    #pragma unroll
    for (int off = 1; off < 64; off <<= 1) s += __shfl_xor(s, off, 64);
    float mean = s * (1.0f / DIM);

    float dx = v.x - mean, dy = v.y - mean, dz = v.z - mean, dw = v.w - mean;
    float s2 = dx * dx + dy * dy + dz * dz + dw * dw;
    #pragma unroll
    for (int off = 1; off < 64; off <<= 1) s2 += __shfl_xor(s2, off, 64);
    float rstd = rsqrtf(s2 * (1.0f / DIM) + LN_EPS);

    float4 gv = *(const float4*)(g + lane * 4);
    float4 bv = *(const float4*)(bb + lane * 4);
    ushort4 o;
    o.x = f2b(dx * rstd * gv.x + bv.x);
    o.y = f2b(dy * rstd * gv.y + bv.y);
    o.z = f2b(dz * rstd * gv.z + bv.z);
    o.w = f2b(dw * rstd * gv.w + bv.w);
    *(ushort4*)(out + (size_t)r * DIM + lane * 4) = o;
}

// ---------------------------------------------------------------------------
// Batched transpose-convert (4x 256x256)
// ---------------------------------------------------------------------------
__global__ __launch_bounds__(256) void tconv4(const float* __restrict__ s0,
                                              const float* __restrict__ s1,
                                              const float* __restrict__ s2,
                                              const float* __restrict__ s3,
                                              ushort* __restrict__ d0,
                                              ushort* __restrict__ d1,
                                              ushort* __restrict__ d2,
                                              ushort* __restrict__ d3) {
    const float* in; ushort* out;
    switch (blockIdx.z) {
        case 0: in = s0; out = d0; break;
        case 1: in = s1; out = d1; break;
        case 2: in = s2; out = d2; break;
        default: in = s3; out = d3; break;
    }
    __shared__ float tile[32][33];
    int tx = threadIdx.x & 31, ty = threadIdx.x >> 5;
    int r0 = blockIdx.y * 32, c0 = blockIdx.x * 32;
    #pragma unroll
    for (int k = 0; k < 4; ++k)
        tile[ty + 8 * k][tx] = in[(size_t)(r0 + ty + 8 * k) * 256 + c0 + tx];
    __syncthreads();
    #pragma unroll
    for (int k = 0; k < 4; ++k)
        out[(size_t)(c0 + ty + 8 * k) * 256 + r0 + tx] = f2b(tile[tx][ty + 8 * k]);
}

// generic tconv for FF weights
__global__ __launch_bounds__(256) void tconv(const float* __restrict__ in,
                                             ushort* __restrict__ out, int R, int C) {
    __shared__ float tile[32][33];
    int tx = threadIdx.x & 31, ty = threadIdx.x >> 5;
    int r0 = blockIdx.y * 32, c0 = blockIdx.x * 32;
    #pragma unroll
    for (int k = 0; k < 4; ++k)
        tile[ty + 8 * k][tx] = in[(size_t)(r0 + ty + 8 * k) * C + c0 + tx];
    __syncthreads();
    #pragma unroll
    for (int k = 0; k < 4; ++k)
        out[(size_t)(c0 + ty + 8 * k) * R + r0 + tx] = f2b(tile[tx][ty + 8 * k]);
}

// merged: w2bd rows (0..255) | Wq row-major bf16 (256..511) | catL copy (512..767)
__global__ __launch_bounds__(256) void prep_mats(const float* __restrict__ W2,
                                                 const float* __restrict__ Wq,
                                                 const ushort* __restrict__ WoT,
                                                 ushort* __restrict__ w2bd,
                                                 ushort* __restrict__ Wq_bf,
                                                 ushort* __restrict__ BtCat) {
    int bb = blockIdx.x, t = threadIdx.x;
    if (bb < 256) {
        float v = ((t >> 6) == (bb >> 6)) ? W2[(bb & 63) * 256 + t] : 0.0f;
        w2bd[bb * 256 + t] = f2b(v);
    } else if (bb < 512) {
        int r = bb - 256;
        Wq_bf[r * 256 + t] = f2b(Wq[r * 256 + t]);
    } else {
        int r = bb - 512;
        BtCat[(size_t)r * 512 + t] = WoT[r * 256 + t];
    }
}

// merged biases
__global__ __launch_bounds__(256) void prep_bias(const float* __restrict__ bq,
                                                 const float* __restrict__ bk,
                                                 const float* __restrict__ bv,
                                                 const float* __restrict__ W2,
                                                 const float* __restrict__ bo,
                                                 const float* __restrict__ br2,
                                                 const float* __restrict__ Wo,
                                                 float* __restrict__ bqkvw,
                                                 float* __restrict__ boc) {
    int bb = blockIdx.x, t = threadIdx.x;
    if (bb == 0) bqkvw[t] = bq[t];
    else if (bb == 1) bqkvw[256 + t] = bk[t];
    else if (bb == 2) bqkvw[512 + t] = bv[t];
    else if (bb == 3) {
        int h = t >> 6, i = t & 63;
        float s = 0.f;
        #pragma unroll 8
        for (int dp = 0; dp < 64; ++dp) s += bq[h * 64 + dp] * W2[i * 256 + h * 64 + dp];
        bqkvw[768 + t] = s;
    } else {
        float s = bo[t];
        #pragma unroll 8
        for (int d = 0; d < 256; ++d) s += br2[d] * Wo[d * 256 + t];
        boc[t] = s;
    }
}

// ---------------------------------------------------------------------------
// MFMA bf16 GEMM: C[M][ldc] = act(A[M][K] @ Bt[N][K]^T + bias) (+res)
// ---------------------------------------------------------------------------
template <int ACT, int OUTBF, int RES>
__global__ __launch_bounds__(256) void gemm_bt(
    const ushort* __restrict__ A, const ushort* __restrict__ Bt,
    const float* __restrict__ bias, const float* __restrict__ res,
    void* __restrict__ Cv, int M, int N, int K, int ldc)
{
    __shared__ ushort As[4096];
    __shared__ ushort Bs[4096];
    const int t = threadIdx.x;
    const int wave = t >> 6, lane = t & 63;
    const int m0 = blockIdx.y * 128, n0 = blockIdx.x * 128;
    const int wr = (wave >> 1) * 64, wc = (wave & 1) * 64;

    f32x4 acc[4][4];
    #pragma unroll
    for (int i = 0; i < 4; ++i)
        #pragma unroll
        for (int j = 0; j < 4; ++j) acc[i][j] = {0.f, 0.f, 0.f, 0.f};

    const int rA0 = (wave * 2 + 0) * 16 + (lane >> 2);
    const int rA1 = (wave * 2 + 1) * 16 + (lane >> 2);
    const int u4 = lane & 3;
    const int sw0 = (rA0 + (rA0 >> 2)) & 3;
    const int sw1 = (rA1 + (rA1 >> 2)) & 3;
    char* ldsA0 = (char*)As + (wave * 2 + 0) * 1024 + lane * 16;
    char* ldsA1 = (char*)As + (wave * 2 + 1) * 1024 + lane * 16;
    char* ldsB0 = (char*)Bs + (wave * 2 + 0) * 1024 + lane * 16;
    char* ldsB1 = (char*)Bs + (wave * 2 + 1) * 1024 + lane * 16;
    const size_t aOff0 = (size_t)(m0 + rA0) * K + (size_t)((u4 ^ sw0) * 8);
    const size_t aOff1 = (size_t)(m0 + rA1) * K + (size_t)((u4 ^ sw1) * 8);
    const size_t bOff0 = (size_t)(n0 + rA0) * K + (size_t)((u4 ^ sw0) * 8);
    const size_t bOff1 = (size_t)(n0 + rA1) * K + (size_t)((u4 ^ sw1) * 8);

    const int cl = lane & 15, gq = lane >> 4;

    for (int k0 = 0; k0 < K; k0 += 32) {
        gload16(A + aOff0 + k0, ldsA0);
        gload16(A + aOff1 + k0, ldsA1);
        gload16(Bt + bOff0 + k0, ldsB0);
        gload16(Bt + bOff1 + k0, ldsB1);
        __syncthreads();

        short8 av[4], bv[4];
        #pragma unroll
        for (int mi = 0; mi < 4; ++mi) {
            int row = wr + mi * 16 + cl;
            int s = (row + (row >> 2)) & 3;
            av[mi] = *(const short8*)((const char*)As + row * 64 + ((gq ^ s) << 4));
            int rowb = wc + mi * 16 + cl;
            int sb = (rowb + (rowb >> 2)) & 3;
            bv[mi] = *(const short8*)((const char*)Bs + rowb * 64 + ((gq ^ sb) << 4));
        }
        #pragma unroll
        for (int mi = 0; mi < 4; ++mi)
            #pragma unroll
            for (int ni = 0; ni < 4; ++ni)
                acc[mi][ni] = __builtin_amdgcn_mfma_f32_16x16x32_bf16(av[mi], bv[ni], acc[mi][ni], 0, 0, 0);
        __syncthreads();
    }

    float* Cf = (float*)Cv;
    ushort* Cb = (ushort*)Cv;
    #pragma unroll
    for (int ni = 0; ni < 4; ++ni) {
        int col = n0 + wc + ni * 16 + cl;
        float bvv = bias ? bias[col] : 0.0f;
        #pragma unroll
        for (int mi = 0; mi < 4; ++mi) {
            #pragma unroll
            for (int r = 0; r < 4; ++r) {
                int row = m0 + wr + mi * 16 + gq * 4 + r;
                float v = acc[mi][ni][r] + bvv;
                if (ACT == 1) v = gelu_f(v);
                if (RES) v += res[(size_t)row * N + col];
                if (OUTBF) Cb[(size_t)row * ldc + col] = f2b(v);
                else       Cf[(size_t)row * ldc + col] = v;
            }
        }
    }
}

// ---------------------------------------------------------------------------
// Attention v5 (validated round 12): hid in-kernel, prologue barrier,
// q/k/v/qw from fused qkvw[16384][1024].
// ---------------------------------------------------------------------------
#define PTS 8
__global__ __launch_bounds__(256) void attn_kernel(
    const int* __restrict__ idx,
    const ushort* __restrict__ qkvw,
    const float* __restrict__ xyz,
    const float* __restrict__ W1,
    const float* __restrict__ b1,
    ushort* __restrict__ ab)
{
    __shared__ float qS[256];
    __shared__ float qwS[256];
    __shared__ float psS[64];
    __shared__ uint4 hidS4[16 * 9];   // [16 rows][stride 144B]
    __shared__ int   nbAll[128];
    __shared__ float w1S[256];
    __shared__ float b1S[64];
    ushort* hidS = (ushort*)hidS4;

    const int t = threadIdx.x;
    const int h = t >> 6, lane = t & 63;
    const int bid = blockIdx.x;
    const int blk = ((bid & 7) << 8) | (bid >> 3);   // XCD-contiguous, bijective
    const int bn0 = blk * PTS;
    const int R0 = blk * (PTS * 16);

    if (t < 128) nbAll[t] = idx[R0 + t];
    w1S[t] = W1[t];
    if (t < 64) b1S[t] = b1[t];
    const float* xb3 = xyz + (size_t)(bn0 >> 12) * NPTS * 3;
    __syncthreads();   // nbAll/w1S/b1S read cross-wave below

    for (int pt = 0; pt < PTS; ++pt) {
        const int bn = bn0 + pt;
        const size_t base = (size_t)(bn >> 12) * NPTS;

        qS[t]  = b2f(qkvw[(size_t)bn * 1024 + t]);
        qwS[t] = b2f(qkvw[(size_t)bn * 1024 + 768 + t]);
        // compute hid rows for this point: j = t>>4 (16 rows), 4 dims/thread
        {
            int n = bn & (NPTS - 1);
            float nx = xb3[n * 3 + 0], ny = xb3[n * 3 + 1], nz = xb3[n * 3 + 2];
            int j = t >> 4;
            int i0 = (t & 15) * 4;
            int m = nbAll[pt * 16 + j];
            float dx = xb3[m * 3 + 0] - nx;
            float dy = xb3[m * 3 + 1] - ny;
            float dz = xb3[m * 3 + 2] - nz;
            float nr = sqrtf(dx * dx + dy * dy + dz * dz);
            uint2 hw;
            float a0 = b1S[i0 + 0] + dx * w1S[i0 + 0] + dy * w1S[64 + i0 + 0] + dz * w1S[128 + i0 + 0] + nr * w1S[192 + i0 + 0];
            float a1 = b1S[i0 + 1] + dx * w1S[i0 + 1] + dy * w1S[64 + i0 + 1] + dz * w1S[128 + i0 + 1] + nr * w1S[192 + i0 + 1];
            float a2 = b1S[i0 + 2] + dx * w1S[i0 + 2] + dy * w1S[64 + i0 + 2] + dz * w1S[128 + i0 + 2] + nr * w1S[192 + i0 + 2];
            float a3 = b1S[i0 + 3] + dx * w1S[i0 + 3] + dy * w1S[64 + i0 + 3] + dz * w1S[128 + i0 + 3] + nr * w1S[192 + i0 + 3];
            hw.x = (uint)f2b(gelu_f(a0)) | ((uint)f2b(gelu_f(a1)) << 16);
            hw.y = (uint)f2b(gelu_f(a2)) | ((uint)f2b(gelu_f(a3)) << 16);
            *(uint2*)(hidS + j * 72 + i0) = hw;
        }
        __syncthreads();

        // logits + softmax (wave h = head h; lane = j*4+sub)
        {
            int j = lane >> 2, sub = lane & 3;
            int m = nbAll[pt * 16 + j];
            const ushort* krow = qkvw + (base + m) * 1024 + 256 + h * 64 + sub * 16;
            uint4 ka = *(const uint4*)krow;
            uint4 kc = *(const uint4*)(krow + 8);
            const float* qp = &qS[h * 64 + sub * 16];
            float d1 = dot8(ka, qp) + dot8(kc, qp + 8);
            const ushort* hrow = hidS + j * 72 + sub * 16;
            uint4 ha = *(const uint4*)hrow;
            uint4 hc = *(const uint4*)(hrow + 8);
            const float* qwp = &qwS[h * 64 + sub * 16];
            float d2 = dot8(ha, qwp) + dot8(hc, qwp + 8);
            float pp = d1 + d2;
            pp += __shfl_xor(pp, 1, 64);
            pp += __shfl_xor(pp, 2, 64);
            pp *= 0.125f;
            float mx = pp;
            mx = fmaxf(mx, __shfl_xor(mx, 4, 64));
            mx = fmaxf(mx, __shfl_xor(mx, 8, 64));
            mx = fmaxf(mx, __shfl_xor(mx, 16, 64));
            mx = fmaxf(mx, __shfl_xor(mx, 32, 64));
            float e = expf(pp - mx);
            float ss = e;
            ss += __shfl_xor(ss, 4, 64);
            ss += __shfl_xor(ss, 8, 64);
            ss += __shfl_xor(ss, 16, 64);
            ss += __shfl_xor(ss, 32, 64);
            float pj = e / ss;
            if (sub == 0) psS[h * 16 + j] = pj;
        }
        __syncthreads();

        // partial + hp
        {
            float o = 0.f, hpv = 0.f;
            #pragma unroll
            for (int j = 0; j < 16; ++j) {
                float p = psS[h * 16 + j];
                int m = nbAll[pt * 16 + j];
                o   += p * b2f(qkvw[(base + m) * 1024 + 512 + t]);
                hpv += p * b2f(hidS[j * 72 + lane]);
            }
            ab[(size_t)bn * 512 + t]       = f2b(o);
            ab[(size_t)bn * 512 + 256 + t] = f2b(hpv);
        }
        __syncthreads();
    }
}

// ---------------------------------------------------------------------------
extern "C" void kernel_launch(void* const* d_in, const int* in_sizes, int n_in,
                              void* d_out, int out_size, void* d_ws, size_t ws_size,
                              hipStream_t stream) {
    const float* xyz    = (const float*)d_in[0];
    const float* feats  = (const float*)d_in[1];
    const float* ln_q_g = (const float*)d_in[2];
    const float* ln_q_b = (const float*)d_in[3];
    const float* Wq     = (const float*)d_in[4];
    const float* bq     = (const float*)d_in[5];
    const float* Wk     = (const float*)d_in[6];
    const float* bk     = (const float*)d_in[7];
    const float* Wv     = (const float*)d_in[8];
    const float* bv     = (const float*)d_in[9];
    const float* W_rel1 = (const float*)d_in[10];
    const float* b_rel1 = (const float*)d_in[11];
    const float* W_rel2 = (const float*)d_in[12];
    const float* b_rel2 = (const float*)d_in[13];
    const float* Wo     = (const float*)d_in[14];
    const float* bo     = (const float*)d_in[15];
    const float* ln_f_g = (const float*)d_in[16];
    const float* ln_f_b = (const float*)d_in[17];
    const float* W_ff1  = (const float*)d_in[18];
    const float* b_ff1  = (const float*)d_in[19];
    const float* W_ff2  = (const float*)d_in[20];
    const float* b_ff2  = (const float*)d_in[21];
    (void)in_sizes; (void)n_in; (void)out_size; (void)ws_size;

    char* ws = (char*)d_ws;
    const size_t MB = 1u << 20;
    int*    idx    = (int*)ws;                        // 1 MB
    ushort* xb     = (ushort*)(ws + 1 * MB);          // 8 MB  (LN out; reused as h)
    ushort* qkvw   = (ushort*)(ws + 9 * MB);          // 32 MB [16384][1024]; feats1 overlays
    ushort* ff1b   = (ushort*)(ws + 41 * MB);         // 32 MB (ff1 out)
    ushort* ab     = (ushort*)(ws + 73 * MB);         // 16 MB [16384][512]
    ushort* BtQKVW = (ushort*)(ws + 89 * MB);         // [1024][256] = 512 KB
    ushort* WoT    = BtQKVW + 262144;                 // 128 KB
    ushort* Wf1T   = WoT + 65536;                     // [1024][256] 512 KB
    ushort* Wf2T   = Wf1T + 262144;                   // [256][1024] 512 KB
    ushort* Wq_bf  = Wf2T + 262144;                   // 128 KB
    ushort* w2bd   = Wq_bf + 65536;                   // 128 KB
    ushort* BtCat  = w2bd + 65536;                    // [256][512] 256 KB
    float*  bqkvw  = (float*)(BtCat + 131072);        // 1024 f32
    float*  boc    = bqkvw + 1024;                    // 256 f32
    float*  feats1 = (float*)(ws + 9 * MB);           // overlays qkvw (dead by then)
    ushort* hb     = xb;                              // overlays xb (dead by then)

    // ---- weight preprocessing ----
    tconv4<<<dim3(8, 8, 4), 256, 0, stream>>>(Wq, Wk, Wv, Wo,
                                              BtQKVW, BtQKVW + 65536, BtQKVW + 131072, WoT);
    tconv<<<dim3(32, 8), 256, 0, stream>>>(W_ff1, Wf1T, 256, 1024);
    tconv<<<dim3(8, 32), 256, 0, stream>>>(W_ff2, Wf2T, 1024, 256);
    prep_mats<<<768, 256, 0, stream>>>(W_rel2, Wq, WoT, w2bd, Wq_bf, BtCat);
    gemm_bt<0, 1, 0><<<dim3(2, 2), 256, 0, stream>>>(w2bd, Wq_bf, nullptr, nullptr,
                                                     BtQKVW + 768 * 256, 256, 256, 256, 256);
    gemm_bt<0, 1, 0><<<dim3(2, 2), 256, 0, stream>>>(WoT, w2bd, nullptr, nullptr,
                                                     BtCat + 256, 256, 256, 256, 512);
    prep_bias<<<5, 256, 0, stream>>>(bq, bk, bv, W_rel2, bo, b_rel2, Wo, bqkvw, boc);

    // ---- main pipeline ----
    knn_kernel<<<MTOT / QPB, 256, 0, stream>>>(xyz, idx);
    ln_kernel<<<MTOT / 4, 256, 0, stream>>>(feats, ln_q_g, ln_q_b, xb);

    // fused q|k|v|qw GEMM: [16384][1024]
    gemm_bt<0, 1, 0><<<dim3(8, 128), 256, 0, stream>>>(xb, BtQKVW, bqkvw, nullptr,
                                                       qkvw, MTOT, 1024, 256, 1024);

    attn_kernel<<<MTOT / PTS, 256, 0, stream>>>(idx, qkvw, xyz, W_rel1, b_rel1, ab);

    // feats1 = [partial|hp] @ BtCat^T + boc + feats   (overlays qkvw)
    gemm_bt<0, 0, 1><<<dim3(2, 128), 256, 0, stream>>>(ab, BtCat, boc, feats, feats1, MTOT, 256, 512, 256);
    ln_kernel<<<MTOT / 4, 256, 0, stream>>>(feats1, ln_f_g, ln_f_b, hb);
    gemm_bt<1, 1, 0><<<dim3(8, 128), 256, 0, stream>>>(hb, Wf1T, b_ff1, nullptr, ff1b, MTOT, 1024, 256, 1024);
    gemm_bt<0, 0, 1><<<dim3(2, 128), 256, 0, stream>>>(ff1b, Wf2T, b_ff2, feats1, (float*)d_out, MTOT, 256, 1024, 256);
}

// Round 17
// 258.151 us; speedup vs baseline: 1.3418x; 1.0461x over previous
//
#include <hip/hip_runtime.h>
#include <hip/hip_bf16.h>
#include <math.h>

#define NB 4
#define NPTS 4096
#define DIM 256
#define KNN 16
#define HID 64
#define FFDIM 1024
#define LN_EPS 1e-5f
#define MTOT (NB * NPTS)
#define KINF 3e38f
#define QPB 8

typedef __attribute__((ext_vector_type(8))) short short8;
typedef __attribute__((ext_vector_type(4))) float f32x4;

__device__ __forceinline__ float gelu_f(float x) {
    return 0.5f * x * (1.0f + erff(x * 0.7071067811865476f));
}
__device__ __forceinline__ float b2f(ushort u) {
    return __uint_as_float(((unsigned)u) << 16);
}
__device__ __forceinline__ ushort f2b(float f) {
    unsigned u = __float_as_uint(f);
    return (ushort)((u + 0x7fffu + ((u >> 16) & 1u)) >> 16);
}
__device__ __forceinline__ void gload16(const void* g, void* l) {
    __builtin_amdgcn_global_load_lds((const __attribute__((address_space(1))) void*)g,
                                     (__attribute__((address_space(3))) void*)l, 16, 0, 0);
}
// dot of 8 bf16 (packed in uint4) with 8 consecutive f32
__device__ __forceinline__ float dot8(uint4 w, const float* q) {
    float s = 0.f;
    s += b2f((ushort)(w.x & 0xffff)) * q[0]; s += b2f((ushort)(w.x >> 16)) * q[1];
    s += b2f((ushort)(w.y & 0xffff)) * q[2]; s += b2f((ushort)(w.y >> 16)) * q[3];
    s += b2f((ushort)(w.z & 0xffff)) * q[4]; s += b2f((ushort)(w.z >> 16)) * q[5];
    s += b2f((ushort)(w.w & 0xffff)) * q[6]; s += b2f((ushort)(w.w >> 16)) * q[7];
    return s;
}

// ---------------------------------------------------------------------------
// KNN v8 (round-13 validated, 68us — FROZEN). xyz staged in LDS once;
// wave w owns queries w and w+4 end-to-end.
// ---------------------------------------------------------------------------
__global__ __launch_bounds__(256) void knn_kernel(const float* __restrict__ xyz,
                                                  int* __restrict__ idx_out) {
    int blk = blockIdx.x;              // MTOT/QPB = 2048
    int bq0 = blk * QPB;
    int b = bq0 >> 12;
    const float* base = xyz + (size_t)b * NPTS * 3;
    int t = threadIdx.x;
    int lane = t & 63, wv = t >> 6;

    __shared__ float pxS[NPTS];        // 16 KB
    __shared__ float pyS[NPTS];
    __shared__ float pzS[NPTS];
    __shared__ int   cnt[QPB];
    __shared__ float cV[QPB][64];
    __shared__ int   cI[QPB][64];

    if (t < QPB) cnt[t] = 0;
    for (int i = t; i < NPTS; i += 256) {
        pxS[i] = base[i * 3 + 0];
        pyS[i] = base[i * 3 + 1];
        pzS[i] = base[i * 3 + 2];
    }
    __syncthreads();                   // the only barrier

    #pragma unroll 1
    for (int rep = 0; rep < 2; ++rep) {
        int qi = wv + 4 * rep;         // wave-private query slot
        int bn = bq0 + qi;
        int n = bn & (NPTS - 1);
        float qx = pxS[n], qy = pyS[n], qz = pzS[n];
        float sqn = qx * qx + qy * qy + qz * qz;

        float d[64];
        float lm = KINF;
        #pragma unroll
        for (int i = 0; i < 64; ++i) {
            int m = lane + 64 * i;
            float x = pxS[m], y = pyS[m], z = pzS[m];
            float sqm = x * x + y * y + z * z;
            float dot = qx * x + qy * y + qz * z;
            float dd = (sqn + sqm) - 2.0f * dot;
            d[i] = (m == n) ? KINF : dd;
            lm = fminf(lm, d[i]);
        }

        float v = lm;
        #pragma unroll
        for (int k = 2; k <= 64; k <<= 1) {
            #pragma unroll
            for (int j = 32; j > 0; j >>= 1) {
                if (j < k) {
                    float ov = __shfl_xor(v, j, 64);
                    bool keepMin = ((lane & k) == 0) == ((lane & j) == 0);
                    if (keepMin == (ov < v)) v = ov;
                }
            }
        }
        float T = __shfl(v, 15, 64);   // 16th-smallest lane-min

        #pragma unroll
        for (int i = 0; i < 64; ++i) {
            if (d[i] <= T) {
                int pos = atomicAdd(&cnt[qi], 1);
                if (pos < 64) { cV[qi][pos] = d[i]; cI[qi][pos] = lane + 64 * i; }
            }
        }

        int nc = cnt[qi]; nc = nc > 64 ? 64 : nc;
        float v2 = (lane < nc) ? cV[qi][lane] : KINF;
        int   m2 = (lane < nc) ? cI[qi][lane] : 0x7fffffff;
        #pragma unroll
        for (int k = 2; k <= 64; k <<= 1) {
            #pragma unroll
            for (int j = 32; j > 0; j >>= 1) {
                if (j < k) {
                    float ov = __shfl_xor(v2, j, 64);
                    int   om = __shfl_xor(m2, j, 64);
                    bool keepMin = ((lane & k) == 0) == ((lane & j) == 0);
                    bool less = (ov < v2) || (ov == v2 && om < m2);
                    if (keepMin == less) { v2 = ov; m2 = om; }
                }
            }
        }
        if (lane < KNN) idx_out[(size_t)bn * KNN + lane] = m2;
    }
}

// ---------------------------------------------------------------------------
// LayerNorm v2 (validated round 16): one wave per row, float4 loads,
// shfl_xor butterflies, packed bf16x4 store.
// ---------------------------------------------------------------------------
__global__ __launch_bounds__(256) void ln_kernel(const float* __restrict__ in,
                                                 const float* __restrict__ g,
                                                 const float* __restrict__ bb,
                                                 ushort* __restrict__ out) {
    int lane = threadIdx.x & 63, wv = threadIdx.x >> 6;
    int r = blockIdx.x * 4 + wv;
    const float* row = in + (size_t)r * DIM;

    float4 v = *(const float4*)(row + lane * 4);
    float s = v.x + v.y + v.z + v.w;
    #pragma unroll
    for (int off = 1; off < 64; off <<= 1) s += __shfl_xor(s, off, 64);
    float mean = s * (1.0f / DIM);

    float dx = v.x - mean, dy = v.y - mean, dz = v.z - mean, dw = v.w - mean;
    float s2 = dx * dx + dy * dy + dz * dz + dw * dw;
    #pragma unroll
    for (int off = 1; off < 64; off <<= 1) s2 += __shfl_xor(s2, off, 64);
    float rstd = rsqrtf(s2 * (1.0f / DIM) + LN_EPS);

    float4 gv = *(const float4*)(g + lane * 4);
    float4 bv = *(const float4*)(bb + lane * 4);
    ushort4 o;
    o.x = f2b(dx * rstd * gv.x + bv.x);
    o.y = f2b(dy * rstd * gv.y + bv.y);
    o.z = f2b(dz * rstd * gv.z + bv.z);
    o.w = f2b(dw * rstd * gv.w + bv.w);
    *(ushort4*)(out + (size_t)r * DIM + lane * 4) = o;
}

// ---------------------------------------------------------------------------
// Batched transpose-convert (4x 256x256)
// ---------------------------------------------------------------------------
__global__ __launch_bounds__(256) void tconv4(const float* __restrict__ s0,
                                              const float* __restrict__ s1,
                                              const float* __restrict__ s2,
                                              const float* __restrict__ s3,
                                              ushort* __restrict__ d0,
                                              ushort* __restrict__ d1,
                                              ushort* __restrict__ d2,
                                              ushort* __restrict__ d3) {
    const float* in; ushort* out;
    switch (blockIdx.z) {
        case 0: in = s0; out = d0; break;
        case 1: in = s1; out = d1; break;
        case 2: in = s2; out = d2; break;
        default: in = s3; out = d3; break;
    }
    __shared__ float tile[32][33];
    int tx = threadIdx.x & 31, ty = threadIdx.x >> 5;
    int r0 = blockIdx.y * 32, c0 = blockIdx.x * 32;
    #pragma unroll
    for (int k = 0; k < 4; ++k)
        tile[ty + 8 * k][tx] = in[(size_t)(r0 + ty + 8 * k) * 256 + c0 + tx];
    __syncthreads();
    #pragma unroll
    for (int k = 0; k < 4; ++k)
        out[(size_t)(c0 + ty + 8 * k) * 256 + r0 + tx] = f2b(tile[tx][ty + 8 * k]);
}

// generic tconv for FF weights
__global__ __launch_bounds__(256) void tconv(const float* __restrict__ in,
                                             ushort* __restrict__ out, int R, int C) {
    __shared__ float tile[32][33];
    int tx = threadIdx.x & 31, ty = threadIdx.x >> 5;
    int r0 = blockIdx.y * 32, c0 = blockIdx.x * 32;
    #pragma unroll
    for (int k = 0; k < 4; ++k)
        tile[ty + 8 * k][tx] = in[(size_t)(r0 + ty + 8 * k) * C + c0 + tx];
    __syncthreads();
    #pragma unroll
    for (int k = 0; k < 4; ++k)
        out[(size_t)(c0 + ty + 8 * k) * R + r0 + tx] = f2b(tile[tx][ty + 8 * k]);
}

// merged: w2bd rows (0..255) | Wq row-major bf16 (256..511) | catL copy (512..767)
__global__ __launch_bounds__(256) void prep_mats(const float* __restrict__ W2,
                                                 const float* __restrict__ Wq,
                                                 const ushort* __restrict__ WoT,
                                                 ushort* __restrict__ w2bd,
                                                 ushort* __restrict__ Wq_bf,
                                                 ushort* __restrict__ BtCat) {
    int bb = blockIdx.x, t = threadIdx.x;
    if (bb < 256) {
        float v = ((t >> 6) == (bb >> 6)) ? W2[(bb & 63) * 256 + t] : 0.0f;
        w2bd[bb * 256 + t] = f2b(v);
    } else if (bb < 512) {
        int r = bb - 256;
        Wq_bf[r * 256 + t] = f2b(Wq[r * 256 + t]);
    } else {
        int r = bb - 512;
        BtCat[(size_t)r * 512 + t] = WoT[r * 256 + t];
    }
}

// merged biases
__global__ __launch_bounds__(256) void prep_bias(const float* __restrict__ bq,
                                                 const float* __restrict__ bk,
                                                 const float* __restrict__ bv,
                                                 const float* __restrict__ W2,
                                                 const float* __restrict__ bo,
                                                 const float* __restrict__ br2,
                                                 const float* __restrict__ Wo,
                                                 float* __restrict__ bqkvw,
                                                 float* __restrict__ boc) {
    int bb = blockIdx.x, t = threadIdx.x;
    if (bb == 0) bqkvw[t] = bq[t];
    else if (bb == 1) bqkvw[256 + t] = bk[t];
    else if (bb == 2) bqkvw[512 + t] = bv[t];
    else if (bb == 3) {
        int h = t >> 6, i = t & 63;
        float s = 0.f;
        #pragma unroll 8
        for (int dp = 0; dp < 64; ++dp) s += bq[h * 64 + dp] * W2[i * 256 + h * 64 + dp];
        bqkvw[768 + t] = s;
    } else {
        float s = bo[t];
        #pragma unroll 8
        for (int d = 0; d < 256; ++d) s += br2[d] * Wo[d * 256 + t];
        boc[t] = s;
    }
}

// ---------------------------------------------------------------------------
// MFMA bf16 GEMM 128x128: C[M][ldc] = act(A@Bt^T + bias) (+res)
// ---------------------------------------------------------------------------
template <int ACT, int OUTBF, int RES>
__global__ __launch_bounds__(256) void gemm_bt(
    const ushort* __restrict__ A, const ushort* __restrict__ Bt,
    const float* __restrict__ bias, const float* __restrict__ res,
    void* __restrict__ Cv, int M, int N, int K, int ldc)
{
    __shared__ ushort As[4096];
    __shared__ ushort Bs[4096];
    const int t = threadIdx.x;
    const int wave = t >> 6, lane = t & 63;
    const int m0 = blockIdx.y * 128, n0 = blockIdx.x * 128;
    const int wr = (wave >> 1) * 64, wc = (wave & 1) * 64;

    f32x4 acc[4][4];
    #pragma unroll
    for (int i = 0; i < 4; ++i)
        #pragma unroll
        for (int j = 0; j < 4; ++j) acc[i][j] = {0.f, 0.f, 0.f, 0.f};

    const int rA0 = (wave * 2 + 0) * 16 + (lane >> 2);
    const int rA1 = (wave * 2 + 1) * 16 + (lane >> 2);
    const int u4 = lane & 3;
    const int sw0 = (rA0 + (rA0 >> 2)) & 3;
    const int sw1 = (rA1 + (rA1 >> 2)) & 3;
    char* ldsA0 = (char*)As + (wave * 2 + 0) * 1024 + lane * 16;
    char* ldsA1 = (char*)As + (wave * 2 + 1) * 1024 + lane * 16;
    char* ldsB0 = (char*)Bs + (wave * 2 + 0) * 1024 + lane * 16;
    char* ldsB1 = (char*)Bs + (wave * 2 + 1) * 1024 + lane * 16;
    const size_t aOff0 = (size_t)(m0 + rA0) * K + (size_t)((u4 ^ sw0) * 8);
    const size_t aOff1 = (size_t)(m0 + rA1) * K + (size_t)((u4 ^ sw1) * 8);
    const size_t bOff0 = (size_t)(n0 + rA0) * K + (size_t)((u4 ^ sw0) * 8);
    const size_t bOff1 = (size_t)(n0 + rA1) * K + (size_t)((u4 ^ sw1) * 8);

    const int cl = lane & 15, gq = lane >> 4;

    for (int k0 = 0; k0 < K; k0 += 32) {
        gload16(A + aOff0 + k0, ldsA0);
        gload16(A + aOff1 + k0, ldsA1);
        gload16(Bt + bOff0 + k0, ldsB0);
        gload16(Bt + bOff1 + k0, ldsB1);
        __syncthreads();

        short8 av[4], bv[4];
        #pragma unroll
        for (int mi = 0; mi < 4; ++mi) {
            int row = wr + mi * 16 + cl;
            int s = (row + (row >> 2)) & 3;
            av[mi] = *(const short8*)((const char*)As + row * 64 + ((gq ^ s) << 4));
            int rowb = wc + mi * 16 + cl;
            int sb = (rowb + (rowb >> 2)) & 3;
            bv[mi] = *(const short8*)((const char*)Bs + rowb * 64 + ((gq ^ sb) << 4));
        }
        #pragma unroll
        for (int mi = 0; mi < 4; ++mi)
            #pragma unroll
            for (int ni = 0; ni < 4; ++ni)
                acc[mi][ni] = __builtin_amdgcn_mfma_f32_16x16x32_bf16(av[mi], bv[ni], acc[mi][ni], 0, 0, 0);
        __syncthreads();
    }

    float* Cf = (float*)Cv;
    ushort* Cb = (ushort*)Cv;
    #pragma unroll
    for (int ni = 0; ni < 4; ++ni) {
        int col = n0 + wc + ni * 16 + cl;
        float bvv = bias ? bias[col] : 0.0f;
        #pragma unroll
        for (int mi = 0; mi < 4; ++mi) {
            #pragma unroll
            for (int r = 0; r < 4; ++r) {
                int row = m0 + wr + mi * 16 + gq * 4 + r;
                float v = acc[mi][ni][r] + bvv;
                if (ACT == 1) v = gelu_f(v);
                if (RES) v += res[(size_t)row * N + col];
                if (OUTBF) Cb[(size_t)row * ldc + col] = f2b(v);
                else       Cf[(size_t)row * ldc + col] = v;
            }
        }
    }
}

// ---------------------------------------------------------------------------
// MFMA bf16 GEMM 128x64 tile (for skinny N=256 GEMMs; 2 blocks/CU instead of
// 1): 4 waves x 32x64 output (acc[2][4]); same staging swizzle and K-order as
// gemm_bt => bitwise-identical results. Cf = A@Bt^T + bias + res (f32 out).
// ---------------------------------------------------------------------------
__global__ __launch_bounds__(256) void gemm_n64(
    const ushort* __restrict__ A, const ushort* __restrict__ Bt,
    const float* __restrict__ bias, const float* __restrict__ res,
    float* __restrict__ Cf, int M, int N, int K, int ldc)
{
    __shared__ ushort As[4096];   // [128][32]
    __shared__ ushort Bs[2048];   // [64][32]
    const int t = threadIdx.x;
    const int wave = t >> 6, lane = t & 63;
    const int m0 = blockIdx.y * 128, n0 = blockIdx.x * 64;
    const int wr = wave * 32;

    f32x4 acc[2][4];
    #pragma unroll
    for (int i = 0; i < 2; ++i)
        #pragma unroll
        for (int j = 0; j < 4; ++j) acc[i][j] = {0.f, 0.f, 0.f, 0.f};

    const int rA0 = (wave * 2 + 0) * 16 + (lane >> 2);
    const int rA1 = (wave * 2 + 1) * 16 + (lane >> 2);
    const int rB  = wave * 16 + (lane >> 2);
    const int u4 = lane & 3;
    const int sw0 = (rA0 + (rA0 >> 2)) & 3;
    const int sw1 = (rA1 + (rA1 >> 2)) & 3;
    const int swB = (rB + (rB >> 2)) & 3;
    char* ldsA0 = (char*)As + (wave * 2 + 0) * 1024 + lane * 16;
    char* ldsA1 = (char*)As + (wave * 2 + 1) * 1024 + lane * 16;
    char* ldsB  = (char*)Bs + wave * 1024 + lane * 16;
    const size_t aOff0 = (size_t)(m0 + rA0) * K + (size_t)((u4 ^ sw0) * 8);
    const size_t aOff1 = (size_t)(m0 + rA1) * K + (size_t)((u4 ^ sw1) * 8);
    const size_t bOff  = (size_t)(n0 + rB) * K + (size_t)((u4 ^ swB) * 8);

    const int cl = lane & 15, gq = lane >> 4;

    for (int k0 = 0; k0 < K; k0 += 32) {
        gload16(A + aOff0 + k0, ldsA0);
        gload16(A + aOff1 + k0, ldsA1);
        gload16(Bt + bOff + k0, ldsB);
        __syncthreads();

        short8 av[2], bv[4];
        #pragma unroll
        for (int mi = 0; mi < 2; ++mi) {
            int row = wr + mi * 16 + cl;
            int s = (row + (row >> 2)) & 3;
            av[mi] = *(const short8*)((const char*)As + row * 64 + ((gq ^ s) << 4));
        }
        #pragma unroll
        for (int ni = 0; ni < 4; ++ni) {
            int rowb = ni * 16 + cl;
            int sb = (rowb + (rowb >> 2)) & 3;
            bv[ni] = *(const short8*)((const char*)Bs + rowb * 64 + ((gq ^ sb) << 4));
        }
        #pragma unroll
        for (int mi = 0; mi < 2; ++mi)
            #pragma unroll
            for (int ni = 0; ni < 4; ++ni)
                acc[mi][ni] = __builtin_amdgcn_mfma_f32_16x16x32_bf16(av[mi], bv[ni], acc[mi][ni], 0, 0, 0);
        __syncthreads();
    }

    #pragma unroll
    for (int ni = 0; ni < 4; ++ni) {
        int col = n0 + ni * 16 + cl;
        float bvv = bias[col];
        #pragma unroll
        for (int mi = 0; mi < 2; ++mi) {
            #pragma unroll
            for (int r = 0; r < 4; ++r) {
                int row = m0 + wr + mi * 16 + gq * 4 + r;
                Cf[(size_t)row * ldc + col] = acc[mi][ni][r] + bvv + res[(size_t)row * N + col];
            }
        }
    }
}

// ---------------------------------------------------------------------------
// Attention v5 (validated round 12): hid in-kernel, prologue barrier,
// q/k/v/qw from fused qkvw[16384][1024].
// ---------------------------------------------------------------------------
#define PTS 8
__global__ __launch_bounds__(256) void attn_kernel(
    const int* __restrict__ idx,
    const ushort* __restrict__ qkvw,
    const float* __restrict__ xyz,
    const float* __restrict__ W1,
    const float* __restrict__ b1,
    ushort* __restrict__ ab)
{
    __shared__ float qS[256];
    __shared__ float qwS[256];
    __shared__ float psS[64];
    __shared__ uint4 hidS4[16 * 9];   // [16 rows][stride 144B]
    __shared__ int   nbAll[128];
    __shared__ float w1S[256];
    __shared__ float b1S[64];
    ushort* hidS = (ushort*)hidS4;

    const int t = threadIdx.x;
    const int h = t >> 6, lane = t & 63;
    const int bid = blockIdx.x;
    const int blk = ((bid & 7) << 8) | (bid >> 3);   // XCD-contiguous, bijective
    const int bn0 = blk * PTS;
    const int R0 = blk * (PTS * 16);

    if (t < 128) nbAll[t] = idx[R0 + t];
    w1S[t] = W1[t];
    if (t < 64) b1S[t] = b1[t];
    const float* xb3 = xyz + (size_t)(bn0 >> 12) * NPTS * 3;
    __syncthreads();   // nbAll/w1S/b1S read cross-wave below

    for (int pt = 0; pt < PTS; ++pt) {
        const int bn = bn0 + pt;
        const size_t base = (size_t)(bn >> 12) * NPTS;

        qS[t]  = b2f(qkvw[(size_t)bn * 1024 + t]);
        qwS[t] = b2f(qkvw[(size_t)bn * 1024 + 768 + t]);
        // compute hid rows for this point: j = t>>4 (16 rows), 4 dims/thread
        {
            int n = bn & (NPTS - 1);
            float nx = xb3[n * 3 + 0], ny = xb3[n * 3 + 1], nz = xb3[n * 3 + 2];
            int j = t >> 4;
            int i0 = (t & 15) * 4;
            int m = nbAll[pt * 16 + j];
            float dx = xb3[m * 3 + 0] - nx;
            float dy = xb3[m * 3 + 1] - ny;
            float dz = xb3[m * 3 + 2] - nz;
            float nr = sqrtf(dx * dx + dy * dy + dz * dz);
            uint2 hw;
            float a0 = b1S[i0 + 0] + dx * w1S[i0 + 0] + dy * w1S[64 + i0 + 0] + dz * w1S[128 + i0 + 0] + nr * w1S[192 + i0 + 0];
            float a1 = b1S[i0 + 1] + dx * w1S[i0 + 1] + dy * w1S[64 + i0 + 1] + dz * w1S[128 + i0 + 1] + nr * w1S[192 + i0 + 1];
            float a2 = b1S[i0 + 2] + dx * w1S[i0 + 2] + dy * w1S[64 + i0 + 2] + dz * w1S[128 + i0 + 2] + nr * w1S[192 + i0 + 2];
            float a3 = b1S[i0 + 3] + dx * w1S[i0 + 3] + dy * w1S[64 + i0 + 3] + dz * w1S[128 + i0 + 3] + nr * w1S[192 + i0 + 3];
            hw.x = (uint)f2b(gelu_f(a0)) | ((uint)f2b(gelu_f(a1)) << 16);
            hw.y = (uint)f2b(gelu_f(a2)) | ((uint)f2b(gelu_f(a3)) << 16);
            *(uint2*)(hidS + j * 72 + i0) = hw;
        }
        __syncthreads();

        // logits + softmax (wave h = head h; lane = j*4+sub)
        {
            int j = lane >> 2, sub = lane & 3;
            int m = nbAll[pt * 16 + j];
            const ushort* krow = qkvw + (base + m) * 1024 + 256 + h * 64 + sub * 16;
            uint4 ka = *(const uint4*)krow;
            uint4 kc = *(const uint4*)(krow + 8);
            const float* qp = &qS[h * 64 + sub * 16];
            float d1 = dot8(ka, qp) + dot8(kc, qp + 8);
            const ushort* hrow = hidS + j * 72 + sub * 16;
            uint4 ha = *(const uint4*)hrow;
            uint4 hc = *(const uint4*)(hrow + 8);
            const float* qwp = &qwS[h * 64 + sub * 16];
            float d2 = dot8(ha, qwp) + dot8(hc, qwp + 8);
            float pp = d1 + d2;
            pp += __shfl_xor(pp, 1, 64);
            pp += __shfl_xor(pp, 2, 64);
            pp *= 0.125f;
            float mx = pp;
            mx = fmaxf(mx, __shfl_xor(mx, 4, 64));
            mx = fmaxf(mx, __shfl_xor(mx, 8, 64));
            mx = fmaxf(mx, __shfl_xor(mx, 16, 64));
            mx = fmaxf(mx, __shfl_xor(mx, 32, 64));
            float e = expf(pp - mx);
            float ss = e;
            ss += __shfl_xor(ss, 4, 64);
            ss += __shfl_xor(ss, 8, 64);
            ss += __shfl_xor(ss, 16, 64);
            ss += __shfl_xor(ss, 32, 64);
            float pj = e / ss;
            if (sub == 0) psS[h * 16 + j] = pj;
        }
        __syncthreads();

        // partial + hp
        {
            float o = 0.f, hpv = 0.f;
            #pragma unroll
            for (int j = 0; j < 16; ++j) {
                float p = psS[h * 16 + j];
                int m = nbAll[pt * 16 + j];
                o   += p * b2f(qkvw[(base + m) * 1024 + 512 + t]);
                hpv += p * b2f(hidS[j * 72 + lane]);
            }
            ab[(size_t)bn * 512 + t]       = f2b(o);
            ab[(size_t)bn * 512 + 256 + t] = f2b(hpv);
        }
        __syncthreads();
    }
}

// ---------------------------------------------------------------------------
extern "C" void kernel_launch(void* const* d_in, const int* in_sizes, int n_in,
                              void* d_out, int out_size, void* d_ws, size_t ws_size,
                              hipStream_t stream) {
    const float* xyz    = (const float*)d_in[0];
    const float* feats  = (const float*)d_in[1];
    const float* ln_q_g = (const float*)d_in[2];
    const float* ln_q_b = (const float*)d_in[3];
    const float* Wq     = (const float*)d_in[4];
    const float* bq     = (const float*)d_in[5];
    const float* Wk     = (const float*)d_in[6];
    const float* bk     = (const float*)d_in[7];
    const float* Wv     = (const float*)d_in[8];
    const float* bv     = (const float*)d_in[9];
    const float* W_rel1 = (const float*)d_in[10];
    const float* b_rel1 = (const float*)d_in[11];
    const float* W_rel2 = (const float*)d_in[12];
    const float* b_rel2 = (const float*)d_in[13];
    const float* Wo     = (const float*)d_in[14];
    const float* bo     = (const float*)d_in[15];
    const float* ln_f_g = (const float*)d_in[16];
    const float* ln_f_b = (const float*)d_in[17];
    const float* W_ff1  = (const float*)d_in[18];
    const float* b_ff1  = (const float*)d_in[19];
    const float* W_ff2  = (const float*)d_in[20];
    const float* b_ff2  = (const float*)d_in[21];
    (void)in_sizes; (void)n_in; (void)out_size; (void)ws_size;

    char* ws = (char*)d_ws;
    const size_t MB = 1u << 20;
    int*    idx    = (int*)ws;                        // 1 MB
    ushort* xb     = (ushort*)(ws + 1 * MB);          // 8 MB  (LN out; reused as h)
    ushort* qkvw   = (ushort*)(ws + 9 * MB);          // 32 MB [16384][1024]; feats1 overlays
    ushort* ff1b   = (ushort*)(ws + 41 * MB);         // 32 MB (ff1 out)
    ushort* ab     = (ushort*)(ws + 73 * MB);         // 16 MB [16384][512]
    ushort* BtQKVW = (ushort*)(ws + 89 * MB);         // [1024][256] = 512 KB
    ushort* WoT    = BtQKVW + 262144;                 // 128 KB
    ushort* Wf1T   = WoT + 65536;                     // [1024][256] 512 KB
    ushort* Wf2T   = Wf1T + 262144;                   // [256][1024] 512 KB
    ushort* Wq_bf  = Wf2T + 262144;                   // 128 KB
    ushort* w2bd   = Wq_bf + 65536;                   // 128 KB
    ushort* BtCat  = w2bd + 65536;                    // [256][512] 256 KB
    float*  bqkvw  = (float*)(BtCat + 131072);        // 1024 f32
    float*  boc    = bqkvw + 1024;                    // 256 f32
    float*  feats1 = (float*)(ws + 9 * MB);           // overlays qkvw (dead by then)
    ushort* hb     = xb;                              // overlays xb (dead by then)

    // ---- weight preprocessing ----
    tconv4<<<dim3(8, 8, 4), 256, 0, stream>>>(Wq, Wk, Wv, Wo,
                                              BtQKVW, BtQKVW + 65536, BtQKVW + 131072, WoT);
    tconv<<<dim3(32, 8), 256, 0, stream>>>(W_ff1, Wf1T, 256, 1024);
    tconv<<<dim3(8, 32), 256, 0, stream>>>(W_ff2, Wf2T, 1024, 256);
    prep_mats<<<768, 256, 0, stream>>>(W_rel2, Wq, WoT, w2bd, Wq_bf, BtCat);
    gemm_bt<0, 1, 0><<<dim3(2, 2), 256, 0, stream>>>(w2bd, Wq_bf, nullptr, nullptr,
                                                     BtQKVW + 768 * 256, 256, 256, 256, 256);
    gemm_bt<0, 1, 0><<<dim3(2, 2), 256, 0, stream>>>(WoT, w2bd, nullptr, nullptr,
                                                     BtCat + 256, 256, 256, 256, 512);
    prep_bias<<<5, 256, 0, stream>>>(bq, bk, bv, W_rel2, bo, b_rel2, Wo, bqkvw, boc);

    // ---- main pipeline ----
    knn_kernel<<<MTOT / QPB, 256, 0, stream>>>(xyz, idx);
    ln_kernel<<<MTOT / 4, 256, 0, stream>>>(feats, ln_q_g, ln_q_b, xb);

    // fused q|k|v|qw GEMM: [16384][1024]
    gemm_bt<0, 1, 0><<<dim3(8, 128), 256, 0, stream>>>(xb, BtQKVW, bqkvw, nullptr,
                                                       qkvw, MTOT, 1024, 256, 1024);

    attn_kernel<<<MTOT / PTS, 256, 0, stream>>>(idx, qkvw, xyz, W_rel1, b_rel1, ab);

    // feats1 = [partial|hp] @ BtCat^T + boc + feats   (128x64 tiles, 2 blk/CU)
    gemm_n64<<<dim3(4, 128), 256, 0, stream>>>(ab, BtCat, boc, feats, feats1, MTOT, 256, 512, 256);
    ln_kernel<<<MTOT / 4, 256, 0, stream>>>(feats1, ln_f_g, ln_f_b, hb);
    gemm_bt<1, 1, 0><<<dim3(8, 128), 256, 0, stream>>>(hb, Wf1T, b_ff1, nullptr, ff1b, MTOT, 1024, 256, 1024);
    // out = ff1 @ W_ff2 + b_ff2 + feats1   (128x64 tiles)
    gemm_n64<<<dim3(4, 128), 256, 0, stream>>>(ff1b, Wf2T, b_ff2, feats1, (float*)d_out, MTOT, 256, 1024, 256);
}

// Round 18
// 240.427 us; speedup vs baseline: 1.4407x; 1.0737x over previous
//
#include <hip/hip_runtime.h>
#include <hip/hip_bf16.h>
#include <math.h>

#define NB 4
#define NPTS 4096
#define DIM 256
#define KNN 16
#define HID 64
#define FFDIM 1024
#define LN_EPS 1e-5f
#define MTOT (NB * NPTS)
#define KINF 3e38f
#define QPB 8

typedef __attribute__((ext_vector_type(8))) short short8;
typedef __attribute__((ext_vector_type(4))) float f32x4;

__device__ __forceinline__ float gelu_f(float x) {
    return 0.5f * x * (1.0f + erff(x * 0.7071067811865476f));
}
__device__ __forceinline__ float b2f(ushort u) {
    return __uint_as_float(((unsigned)u) << 16);
}
__device__ __forceinline__ ushort f2b(float f) {
    unsigned u = __float_as_uint(f);
    return (ushort)((u + 0x7fffu + ((u >> 16) & 1u)) >> 16);
}
__device__ __forceinline__ void gload16(const void* g, void* l) {
    __builtin_amdgcn_global_load_lds((const __attribute__((address_space(1))) void*)g,
                                     (__attribute__((address_space(3))) void*)l, 16, 0, 0);
}
// dot of 8 bf16 (packed in uint4) with 8 consecutive f32
__device__ __forceinline__ float dot8(uint4 w, const float* q) {
    float s = 0.f;
    s += b2f((ushort)(w.x & 0xffff)) * q[0]; s += b2f((ushort)(w.x >> 16)) * q[1];
    s += b2f((ushort)(w.y & 0xffff)) * q[2]; s += b2f((ushort)(w.y >> 16)) * q[3];
    s += b2f((ushort)(w.z & 0xffff)) * q[4]; s += b2f((ushort)(w.z >> 16)) * q[5];
    s += b2f((ushort)(w.w & 0xffff)) * q[6]; s += b2f((ushort)(w.w >> 16)) * q[7];
    return s;
}

// ---------------------------------------------------------------------------
// KNN v8 (round-13 validated, 68us — FROZEN). xyz staged in LDS once;
// wave w owns queries w and w+4 end-to-end.
// ---------------------------------------------------------------------------
__global__ __launch_bounds__(256) void knn_kernel(const float* __restrict__ xyz,
                                                  int* __restrict__ idx_out) {
    int blk = blockIdx.x;              // MTOT/QPB = 2048
    int bq0 = blk * QPB;
    int b = bq0 >> 12;
    const float* base = xyz + (size_t)b * NPTS * 3;
    int t = threadIdx.x;
    int lane = t & 63, wv = t >> 6;

    __shared__ float pxS[NPTS];        // 16 KB
    __shared__ float pyS[NPTS];
    __shared__ float pzS[NPTS];
    __shared__ int   cnt[QPB];
    __shared__ float cV[QPB][64];
    __shared__ int   cI[QPB][64];

    if (t < QPB) cnt[t] = 0;
    for (int i = t; i < NPTS; i += 256) {
        pxS[i] = base[i * 3 + 0];
        pyS[i] = base[i * 3 + 1];
        pzS[i] = base[i * 3 + 2];
    }
    __syncthreads();                   // the only barrier

    #pragma unroll 1
    for (int rep = 0; rep < 2; ++rep) {
        int qi = wv + 4 * rep;         // wave-private query slot
        int bn = bq0 + qi;
        int n = bn & (NPTS - 1);
        float qx = pxS[n], qy = pyS[n], qz = pzS[n];
        float sqn = qx * qx + qy * qy + qz * qz;

        float d[64];
        float lm = KINF;
        #pragma unroll
        for (int i = 0; i < 64; ++i) {
            int m = lane + 64 * i;
            float x = pxS[m], y = pyS[m], z = pzS[m];
            float sqm = x * x + y * y + z * z;
            float dot = qx * x + qy * y + qz * z;
            float dd = (sqn + sqm) - 2.0f * dot;
            d[i] = (m == n) ? KINF : dd;
            lm = fminf(lm, d[i]);
        }

        float v = lm;
        #pragma unroll
        for (int k = 2; k <= 64; k <<= 1) {
            #pragma unroll
            for (int j = 32; j > 0; j >>= 1) {
                if (j < k) {
                    float ov = __shfl_xor(v, j, 64);
                    bool keepMin = ((lane & k) == 0) == ((lane & j) == 0);
                    if (keepMin == (ov < v)) v = ov;
                }
            }
        }
        float T = __shfl(v, 15, 64);   // 16th-smallest lane-min

        #pragma unroll
        for (int i = 0; i < 64; ++i) {
            if (d[i] <= T) {
                int pos = atomicAdd(&cnt[qi], 1);
                if (pos < 64) { cV[qi][pos] = d[i]; cI[qi][pos] = lane + 64 * i; }
            }
        }

        int nc = cnt[qi]; nc = nc > 64 ? 64 : nc;
        float v2 = (lane < nc) ? cV[qi][lane] : KINF;
        int   m2 = (lane < nc) ? cI[qi][lane] : 0x7fffffff;
        #pragma unroll
        for (int k = 2; k <= 64; k <<= 1) {
            #pragma unroll
            for (int j = 32; j > 0; j >>= 1) {
                if (j < k) {
                    float ov = __shfl_xor(v2, j, 64);
                    int   om = __shfl_xor(m2, j, 64);
                    bool keepMin = ((lane & k) == 0) == ((lane & j) == 0);
                    bool less = (ov < v2) || (ov == v2 && om < m2);
                    if (keepMin == less) { v2 = ov; m2 = om; }
                }
            }
        }
        if (lane < KNN) idx_out[(size_t)bn * KNN + lane] = m2;
    }
}

// ---------------------------------------------------------------------------
// LayerNorm v2 (validated round 16): one wave per row, float4 loads,
// shfl_xor butterflies, packed bf16x4 store.
// ---------------------------------------------------------------------------
__global__ __launch_bounds__(256) void ln_kernel(const float* __restrict__ in,
                                                 const float* __restrict__ g,
                                                 const float* __restrict__ bb,
                                                 ushort* __restrict__ out) {
    int lane = threadIdx.x & 63, wv = threadIdx.x >> 6;
    int r = blockIdx.x * 4 + wv;
    const float* row = in + (size_t)r * DIM;

    float4 v = *(const float4*)(row + lane * 4);
    float s = v.x + v.y + v.z + v.w;
    #pragma unroll
    for (int off = 1; off < 64; off <<= 1) s += __shfl_xor(s, off, 64);
    float mean = s * (1.0f / DIM);

    float dx = v.x - mean, dy = v.y - mean, dz = v.z - mean, dw = v.w - mean;
    float s2 = dx * dx + dy * dy + dz * dz + dw * dw;
    #pragma unroll
    for (int off = 1; off < 64; off <<= 1) s2 += __shfl_xor(s2, off, 64);
    float rstd = rsqrtf(s2 * (1.0f / DIM) + LN_EPS);

    float4 gv = *(const float4*)(g + lane * 4);
    float4 bv = *(const float4*)(bb + lane * 4);
    ushort4 o;
    o.x = f2b(dx * rstd * gv.x + bv.x);
    o.y = f2b(dy * rstd * gv.y + bv.y);
    o.z = f2b(dz * rstd * gv.z + bv.z);
    o.w = f2b(dw * rstd * gv.w + bv.w);
    *(ushort4*)(out + (size_t)r * DIM + lane * 4) = o;
}

// ---------------------------------------------------------------------------
// tconv_all: ALL six weight transposes in one launch (768 tile-blocks).
//  tiles 0..255   : 4 square 256x256 (Wq,Wk,Wv,Wo), 64 tiles each
//  tiles 256..511 : W_ff1 (256x1024), c=local&31, r=local>>5
//  tiles 512..767 : W_ff2 (1024x256), c=local&7,  r=local>>3
// Same 32x32 tile body as the validated tconv => bit-identical outputs.
// ---------------------------------------------------------------------------
__device__ __forceinline__ void ttile(const float* __restrict__ in,
                                      ushort* __restrict__ out, int R, int C,
                                      int r0, int c0, float (*tile)[33]) {
    int tx = threadIdx.x & 31, ty = threadIdx.x >> 5;
    #pragma unroll
    for (int k = 0; k < 4; ++k)
        tile[ty + 8 * k][tx] = in[(size_t)(r0 + ty + 8 * k) * C + c0 + tx];
    __syncthreads();
    #pragma unroll
    for (int k = 0; k < 4; ++k)
        out[(size_t)(c0 + ty + 8 * k) * R + r0 + tx] = f2b(tile[tx][ty + 8 * k]);
}

__global__ __launch_bounds__(256) void tconv_all(
    const float* __restrict__ Wq, const float* __restrict__ Wk,
    const float* __restrict__ Wv, const float* __restrict__ Wo,
    const float* __restrict__ Wff1, const float* __restrict__ Wff2,
    ushort* __restrict__ BtQKVW, ushort* __restrict__ WoT,
    ushort* __restrict__ Wf1T, ushort* __restrict__ Wf2T)
{
    __shared__ float tile[32][33];
    int tid = blockIdx.x;
    if (tid < 256) {
        int m = tid >> 6, local = tid & 63;
        int r0 = (local >> 3) * 32, c0 = (local & 7) * 32;
        const float* in = (m == 0) ? Wq : (m == 1) ? Wk : (m == 2) ? Wv : Wo;
        ushort* out = (m == 3) ? WoT : BtQKVW + m * 65536;
        ttile(in, out, 256, 256, r0, c0, tile);
    } else if (tid < 512) {
        int local = tid - 256;
        int r0 = (local >> 5) * 32, c0 = (local & 31) * 32;
        ttile(Wff1, Wf1T, 256, 1024, r0, c0, tile);
    } else {
        int local = tid - 512;
        int r0 = (local >> 3) * 32, c0 = (local & 7) * 32;
        ttile(Wff2, Wf2T, 1024, 256, r0, c0, tile);
    }
}

// ---------------------------------------------------------------------------
// prep_mb: prep_mats (blocks 0..767) + prep_bias (blocks 768..772), merged.
// ---------------------------------------------------------------------------
__global__ __launch_bounds__(256) void prep_mb(const float* __restrict__ W2,
                                               const float* __restrict__ Wq,
                                               const ushort* __restrict__ WoT,
                                               const float* __restrict__ bq,
                                               const float* __restrict__ bk,
                                               const float* __restrict__ bv,
                                               const float* __restrict__ bo,
                                               const float* __restrict__ br2,
                                               const float* __restrict__ Wo,
                                               ushort* __restrict__ w2bd,
                                               ushort* __restrict__ Wq_bf,
                                               ushort* __restrict__ BtCat,
                                               float* __restrict__ bqkvw,
                                               float* __restrict__ boc) {
    int bb = blockIdx.x, t = threadIdx.x;
    if (bb < 256) {
        float v = ((t >> 6) == (bb >> 6)) ? W2[(bb & 63) * 256 + t] : 0.0f;
        w2bd[bb * 256 + t] = f2b(v);
    } else if (bb < 512) {
        int r = bb - 256;
        Wq_bf[r * 256 + t] = f2b(Wq[r * 256 + t]);
    } else if (bb < 768) {
        int r = bb - 512;
        BtCat[(size_t)r * 512 + t] = WoT[r * 256 + t];
    } else {
        int pb = bb - 768;
        if (pb == 0) bqkvw[t] = bq[t];
        else if (pb == 1) bqkvw[256 + t] = bk[t];
        else if (pb == 2) bqkvw[512 + t] = bv[t];
        else if (pb == 3) {
            int h = t >> 6, i = t & 63;
            float s = 0.f;
            #pragma unroll 8
            for (int dp = 0; dp < 64; ++dp) s += bq[h * 64 + dp] * W2[i * 256 + h * 64 + dp];
            bqkvw[768 + t] = s;
        } else {
            float s = bo[t];
            #pragma unroll 8
            for (int d = 0; d < 256; ++d) s += br2[d] * Wo[d * 256 + t];
            boc[t] = s;
        }
    }
}

// ---------------------------------------------------------------------------
// MFMA bf16 GEMM 128x128: C[M][ldc] = act(A@Bt^T + bias) (+res)
// ---------------------------------------------------------------------------
template <int ACT, int OUTBF, int RES>
__global__ __launch_bounds__(256) void gemm_bt(
    const ushort* __restrict__ A, const ushort* __restrict__ Bt,
    const float* __restrict__ bias, const float* __restrict__ res,
    void* __restrict__ Cv, int M, int N, int K, int ldc)
{
    __shared__ ushort As[4096];
    __shared__ ushort Bs[4096];
    const int t = threadIdx.x;
    const int wave = t >> 6, lane = t & 63;
    const int m0 = blockIdx.y * 128, n0 = blockIdx.x * 128;
    const int wr = (wave >> 1) * 64, wc = (wave & 1) * 64;

    f32x4 acc[4][4];
    #pragma unroll
    for (int i = 0; i < 4; ++i)
        #pragma unroll
        for (int j = 0; j < 4; ++j) acc[i][j] = {0.f, 0.f, 0.f, 0.f};

    const int rA0 = (wave * 2 + 0) * 16 + (lane >> 2);
    const int rA1 = (wave * 2 + 1) * 16 + (lane >> 2);
    const int u4 = lane & 3;
    const int sw0 = (rA0 + (rA0 >> 2)) & 3;
    const int sw1 = (rA1 + (rA1 >> 2)) & 3;
    char* ldsA0 = (char*)As + (wave * 2 + 0) * 1024 + lane * 16;
    char* ldsA1 = (char*)As + (wave * 2 + 1) * 1024 + lane * 16;
    char* ldsB0 = (char*)Bs + (wave * 2 + 0) * 1024 + lane * 16;
    char* ldsB1 = (char*)Bs + (wave * 2 + 1) * 1024 + lane * 16;
    const size_t aOff0 = (size_t)(m0 + rA0) * K + (size_t)((u4 ^ sw0) * 8);
    const size_t aOff1 = (size_t)(m0 + rA1) * K + (size_t)((u4 ^ sw1) * 8);
    const size_t bOff0 = (size_t)(n0 + rA0) * K + (size_t)((u4 ^ sw0) * 8);
    const size_t bOff1 = (size_t)(n0 + rA1) * K + (size_t)((u4 ^ sw1) * 8);

    const int cl = lane & 15, gq = lane >> 4;

    for (int k0 = 0; k0 < K; k0 += 32) {
        gload16(A + aOff0 + k0, ldsA0);
        gload16(A + aOff1 + k0, ldsA1);
        gload16(Bt + bOff0 + k0, ldsB0);
        gload16(Bt + bOff1 + k0, ldsB1);
        __syncthreads();

        short8 av[4], bv[4];
        #pragma unroll
        for (int mi = 0; mi < 4; ++mi) {
            int row = wr + mi * 16 + cl;
            int s = (row + (row >> 2)) & 3;
            av[mi] = *(const short8*)((const char*)As + row * 64 + ((gq ^ s) << 4));
            int rowb = wc + mi * 16 + cl;
            int sb = (rowb + (rowb >> 2)) & 3;
            bv[mi] = *(const short8*)((const char*)Bs + rowb * 64 + ((gq ^ sb) << 4));
        }
        #pragma unroll
        for (int mi = 0; mi < 4; ++mi)
            #pragma unroll
            for (int ni = 0; ni < 4; ++ni)
                acc[mi][ni] = __builtin_amdgcn_mfma_f32_16x16x32_bf16(av[mi], bv[ni], acc[mi][ni], 0, 0, 0);
        __syncthreads();
    }

    float* Cf = (float*)Cv;
    ushort* Cb = (ushort*)Cv;
    #pragma unroll
    for (int ni = 0; ni < 4; ++ni) {
        int col = n0 + wc + ni * 16 + cl;
        float bvv = bias ? bias[col] : 0.0f;
        #pragma unroll
        for (int mi = 0; mi < 4; ++mi) {
            #pragma unroll
            for (int r = 0; r < 4; ++r) {
                int row = m0 + wr + mi * 16 + gq * 4 + r;
                float v = acc[mi][ni][r] + bvv;
                if (ACT == 1) v = gelu_f(v);
                if (RES) v += res[(size_t)row * N + col];
                if (OUTBF) Cb[(size_t)row * ldc + col] = f2b(v);
                else       Cf[(size_t)row * ldc + col] = v;
            }
        }
    }
}

// ---------------------------------------------------------------------------
// gemm_pre2: both tiny 256^3 weight GEMMs in ONE 8-block dispatch.
// blocks 0-3: WqwT = w2bd @ Wq_bf^T -> BtQKVW rows 768.. (ldc 256)
// blocks 4-7: W2Wo = WoT @ w2bd^T  -> BtCat右 (ldc 512)
// Body identical to gemm_bt<0,1,0>.
// ---------------------------------------------------------------------------
__global__ __launch_bounds__(256) void gemm_pre2(
    const ushort* __restrict__ w2bd, const ushort* __restrict__ Wq_bf,
    const ushort* __restrict__ WoT, ushort* __restrict__ outA,
    ushort* __restrict__ outB)
{
    __shared__ ushort As[4096];
    __shared__ ushort Bs[4096];
    int g = blockIdx.x;
    const ushort* A;  const ushort* Bt;  ushort* Cb;  int ldc;
    int bx, by;
    if (g < 4) { A = w2bd; Bt = Wq_bf; Cb = outA; ldc = 256; bx = g & 1; by = g >> 1; }
    else       { A = WoT;  Bt = w2bd;  Cb = outB; ldc = 512; bx = (g - 4) & 1; by = (g - 4) >> 1; }
    const int K = 256;
    const int t = threadIdx.x;
    const int wave = t >> 6, lane = t & 63;
    const int m0 = by * 128, n0 = bx * 128;
    const int wr = (wave >> 1) * 64, wc = (wave & 1) * 64;

    f32x4 acc[4][4];
    #pragma unroll
    for (int i = 0; i < 4; ++i)
        #pragma unroll
        for (int j = 0; j < 4; ++j) acc[i][j] = {0.f, 0.f, 0.f, 0.f};

    const int rA0 = (wave * 2 + 0) * 16 + (lane >> 2);
    const int rA1 = (wave * 2 + 1) * 16 + (lane >> 2);
    const int u4 = lane & 3;
    const int sw0 = (rA0 + (rA0 >> 2)) & 3;
    const int sw1 = (rA1 + (rA1 >> 2)) & 3;
    char* ldsA0 = (char*)As + (wave * 2 + 0) * 1024 + lane * 16;
    char* ldsA1 = (char*)As + (wave * 2 + 1) * 1024 + lane * 16;
    char* ldsB0 = (char*)Bs + (wave * 2 + 0) * 1024 + lane * 16;
    char* ldsB1 = (char*)Bs + (wave * 2 + 1) * 1024 + lane * 16;
    const size_t aOff0 = (size_t)(m0 + rA0) * K + (size_t)((u4 ^ sw0) * 8);
    const size_t aOff1 = (size_t)(m0 + rA1) * K + (size_t)((u4 ^ sw1) * 8);
    const size_t bOff0 = (size_t)(n0 + rA0) * K + (size_t)((u4 ^ sw0) * 8);
    const size_t bOff1 = (size_t)(n0 + rA1) * K + (size_t)((u4 ^ sw1) * 8);
    const int cl = lane & 15, gq = lane >> 4;

    for (int k0 = 0; k0 < K; k0 += 32) {
        gload16(A + aOff0 + k0, ldsA0);
        gload16(A + aOff1 + k0, ldsA1);
        gload16(Bt + bOff0 + k0, ldsB0);
        gload16(Bt + bOff1 + k0, ldsB1);
        __syncthreads();
        short8 av[4], bv[4];
        #pragma unroll
        for (int mi = 0; mi < 4; ++mi) {
            int row = wr + mi * 16 + cl;
            int s = (row + (row >> 2)) & 3;
            av[mi] = *(const short8*)((const char*)As + row * 64 + ((gq ^ s) << 4));
            int rowb = wc + mi * 16 + cl;
            int sb = (rowb + (rowb >> 2)) & 3;
            bv[mi] = *(const short8*)((const char*)Bs + rowb * 64 + ((gq ^ sb) << 4));
        }
        #pragma unroll
        for (int mi = 0; mi < 4; ++mi)
            #pragma unroll
            for (int ni = 0; ni < 4; ++ni)
                acc[mi][ni] = __builtin_amdgcn_mfma_f32_16x16x32_bf16(av[mi], bv[ni], acc[mi][ni], 0, 0, 0);
        __syncthreads();
    }

    #pragma unroll
    for (int ni = 0; ni < 4; ++ni) {
        int col = n0 + wc + ni * 16 + cl;
        #pragma unroll
        for (int mi = 0; mi < 4; ++mi) {
            #pragma unroll
            for (int r = 0; r < 4; ++r) {
                int row = m0 + wr + mi * 16 + gq * 4 + r;
                Cb[(size_t)row * ldc + col] = f2b(acc[mi][ni][r]);
            }
        }
    }
}

// ---------------------------------------------------------------------------
// MFMA bf16 GEMM 128x64 tile (validated round 17).
// ---------------------------------------------------------------------------
__global__ __launch_bounds__(256) void gemm_n64(
    const ushort* __restrict__ A, const ushort* __restrict__ Bt,
    const float* __restrict__ bias, const float* __restrict__ res,
    float* __restrict__ Cf, int M, int N, int K, int ldc)
{
    __shared__ ushort As[4096];   // [128][32]
    __shared__ ushort Bs[2048];   // [64][32]
    const int t = threadIdx.x;
    const int wave = t >> 6, lane = t & 63;
    const int m0 = blockIdx.y * 128, n0 = blockIdx.x * 64;
    const int wr = wave * 32;

    f32x4 acc[2][4];
    #pragma unroll
    for (int i = 0; i < 2; ++i)
        #pragma unroll
        for (int j = 0; j < 4; ++j) acc[i][j] = {0.f, 0.f, 0.f, 0.f};

    const int rA0 = (wave * 2 + 0) * 16 + (lane >> 2);
    const int rA1 = (wave * 2 + 1) * 16 + (lane >> 2);
    const int rB  = wave * 16 + (lane >> 2);
    const int u4 = lane & 3;
    const int sw0 = (rA0 + (rA0 >> 2)) & 3;
    const int sw1 = (rA1 + (rA1 >> 2)) & 3;
    const int swB = (rB + (rB >> 2)) & 3;
    char* ldsA0 = (char*)As + (wave * 2 + 0) * 1024 + lane * 16;
    char* ldsA1 = (char*)As + (wave * 2 + 1) * 1024 + lane * 16;
    char* ldsB  = (char*)Bs + wave * 1024 + lane * 16;
    const size_t aOff0 = (size_t)(m0 + rA0) * K + (size_t)((u4 ^ sw0) * 8);
    const size_t aOff1 = (size_t)(m0 + rA1) * K + (size_t)((u4 ^ sw1) * 8);
    const size_t bOff  = (size_t)(n0 + rB) * K + (size_t)((u4 ^ swB) * 8);

    const int cl = lane & 15, gq = lane >> 4;

    for (int k0 = 0; k0 < K; k0 += 32) {
        gload16(A + aOff0 + k0, ldsA0);
        gload16(A + aOff1 + k0, ldsA1);
        gload16(Bt + bOff + k0, ldsB);
        __syncthreads();

        short8 av[2], bv[4];
        #pragma unroll
        for (int mi = 0; mi < 2; ++mi) {
            int row = wr + mi * 16 + cl;
            int s = (row + (row >> 2)) & 3;
            av[mi] = *(const short8*)((const char*)As + row * 64 + ((gq ^ s) << 4));
        }
        #pragma unroll
        for (int ni = 0; ni < 4; ++ni) {
            int rowb = ni * 16 + cl;
            int sb = (rowb + (rowb >> 2)) & 3;
            bv[ni] = *(const short8*)((const char*)Bs + rowb * 64 + ((gq ^ sb) << 4));
        }
        #pragma unroll
        for (int mi = 0; mi < 2; ++mi)
            #pragma unroll
            for (int ni = 0; ni < 4; ++ni)
                acc[mi][ni] = __builtin_amdgcn_mfma_f32_16x16x32_bf16(av[mi], bv[ni], acc[mi][ni], 0, 0, 0);
        __syncthreads();
    }

    #pragma unroll
    for (int ni = 0; ni < 4; ++ni) {
        int col = n0 + ni * 16 + cl;
        float bvv = bias[col];
        #pragma unroll
        for (int mi = 0; mi < 2; ++mi) {
            #pragma unroll
            for (int r = 0; r < 4; ++r) {
                int row = m0 + wr + mi * 16 + gq * 4 + r;
                Cf[(size_t)row * ldc + col] = acc[mi][ni][r] + bvv + res[(size_t)row * N + col];
            }
        }
    }
}

// ---------------------------------------------------------------------------
// Attention v5 (validated round 12): hid in-kernel, prologue barrier,
// q/k/v/qw from fused qkvw[16384][1024].
// ---------------------------------------------------------------------------
#define PTS 8
__global__ __launch_bounds__(256) void attn_kernel(
    const int* __restrict__ idx,
    const ushort* __restrict__ qkvw,
    const float* __restrict__ xyz,
    const float* __restrict__ W1,
    const float* __restrict__ b1,
    ushort* __restrict__ ab)
{
    __shared__ float qS[256];
    __shared__ float qwS[256];
    __shared__ float psS[64];
    __shared__ uint4 hidS4[16 * 9];   // [16 rows][stride 144B]
    __shared__ int   nbAll[128];
    __shared__ float w1S[256];
    __shared__ float b1S[64];
    ushort* hidS = (ushort*)hidS4;

    const int t = threadIdx.x;
    const int h = t >> 6, lane = t & 63;
    const int bid = blockIdx.x;
    const int blk = ((bid & 7) << 8) | (bid >> 3);   // XCD-contiguous, bijective
    const int bn0 = blk * PTS;
    const int R0 = blk * (PTS * 16);

    if (t < 128) nbAll[t] = idx[R0 + t];
    w1S[t] = W1[t];
    if (t < 64) b1S[t] = b1[t];
    const float* xb3 = xyz + (size_t)(bn0 >> 12) * NPTS * 3;
    __syncthreads();   // nbAll/w1S/b1S read cross-wave below

    for (int pt = 0; pt < PTS; ++pt) {
        const int bn = bn0 + pt;
        const size_t base = (size_t)(bn >> 12) * NPTS;

        qS[t]  = b2f(qkvw[(size_t)bn * 1024 + t]);
        qwS[t] = b2f(qkvw[(size_t)bn * 1024 + 768 + t]);
        // compute hid rows for this point: j = t>>4 (16 rows), 4 dims/thread
        {
            int n = bn & (NPTS - 1);
            float nx = xb3[n * 3 + 0], ny = xb3[n * 3 + 1], nz = xb3[n * 3 + 2];
            int j = t >> 4;
            int i0 = (t & 15) * 4;
            int m = nbAll[pt * 16 + j];
            float dx = xb3[m * 3 + 0] - nx;
            float dy = xb3[m * 3 + 1] - ny;
            float dz = xb3[m * 3 + 2] - nz;
            float nr = sqrtf(dx * dx + dy * dy + dz * dz);
            uint2 hw;
            float a0 = b1S[i0 + 0] + dx * w1S[i0 + 0] + dy * w1S[64 + i0 + 0] + dz * w1S[128 + i0 + 0] + nr * w1S[192 + i0 + 0];
            float a1 = b1S[i0 + 1] + dx * w1S[i0 + 1] + dy * w1S[64 + i0 + 1] + dz * w1S[128 + i0 + 1] + nr * w1S[192 + i0 + 1];
            float a2 = b1S[i0 + 2] + dx * w1S[i0 + 2] + dy * w1S[64 + i0 + 2] + dz * w1S[128 + i0 + 2] + nr * w1S[192 + i0 + 2];
            float a3 = b1S[i0 + 3] + dx * w1S[i0 + 3] + dy * w1S[64 + i0 + 3] + dz * w1S[128 + i0 + 3] + nr * w1S[192 + i0 + 3];
            hw.x = (uint)f2b(gelu_f(a0)) | ((uint)f2b(gelu_f(a1)) << 16);
            hw.y = (uint)f2b(gelu_f(a2)) | ((uint)f2b(gelu_f(a3)) << 16);
            *(uint2*)(hidS + j * 72 + i0) = hw;
        }
        __syncthreads();

        // logits + softmax (wave h = head h; lane = j*4+sub)
        {
            int j = lane >> 2, sub = lane & 3;
            int m = nbAll[pt * 16 + j];
            const ushort* krow = qkvw + (base + m) * 1024 + 256 + h * 64 + sub * 16;
            uint4 ka = *(const uint4*)krow;
            uint4 kc = *(const uint4*)(krow + 8);
            const float* qp = &qS[h * 64 + sub * 16];
            float d1 = dot8(ka, qp) + dot8(kc, qp + 8);
            const ushort* hrow = hidS + j * 72 + sub * 16;
            uint4 ha = *(const uint4*)hrow;
            uint4 hc = *(const uint4*)(hrow + 8);
            const float* qwp = &qwS[h * 64 + sub * 16];
            float d2 = dot8(ha, qwp) + dot8(hc, qwp + 8);
            float pp = d1 + d2;
            pp += __shfl_xor(pp, 1, 64);
            pp += __shfl_xor(pp, 2, 64);
            pp *= 0.125f;
            float mx = pp;
            mx = fmaxf(mx, __shfl_xor(mx, 4, 64));
            mx = fmaxf(mx, __shfl_xor(mx, 8, 64));
            mx = fmaxf(mx, __shfl_xor(mx, 16, 64));
            mx = fmaxf(mx, __shfl_xor(mx, 32, 64));
            float e = expf(pp - mx);
            float ss = e;
            ss += __shfl_xor(ss, 4, 64);
            ss += __shfl_xor(ss, 8, 64);
            ss += __shfl_xor(ss, 16, 64);
            ss += __shfl_xor(ss, 32, 64);
            float pj = e / ss;
            if (sub == 0) psS[h * 16 + j] = pj;
        }
        __syncthreads();

        // partial + hp
        {
            float o = 0.f, hpv = 0.f;
            #pragma unroll
            for (int j = 0; j < 16; ++j) {
                float p = psS[h * 16 + j];
                int m = nbAll[pt * 16 + j];
                o   += p * b2f(qkvw[(base + m) * 1024 + 512 + t]);
                hpv += p * b2f(hidS[j * 72 + lane]);
            }
            ab[(size_t)bn * 512 + t]       = f2b(o);
            ab[(size_t)bn * 512 + 256 + t] = f2b(hpv);
        }
        __syncthreads();
    }
}

// ---------------------------------------------------------------------------
extern "C" void kernel_launch(void* const* d_in, const int* in_sizes, int n_in,
                              void* d_out, int out_size, void* d_ws, size_t ws_size,
                              hipStream_t stream) {
    const float* xyz    = (const float*)d_in[0];
    const float* feats  = (const float*)d_in[1];
    const float* ln_q_g = (const float*)d_in[2];
    const float* ln_q_b = (const float*)d_in[3];
    const float* Wq     = (const float*)d_in[4];
    const float* bq     = (const float*)d_in[5];
    const float* Wk     = (const float*)d_in[6];
    const float* bk     = (const float*)d_in[7];
    const float* Wv     = (const float*)d_in[8];
    const float* bv     = (const float*)d_in[9];
    const float* W_rel1 = (const float*)d_in[10];
    const float* b_rel1 = (const float*)d_in[11];
    const float* W_rel2 = (const float*)d_in[12];
    const float* b_rel2 = (const float*)d_in[13];
    const float* Wo     = (const float*)d_in[14];
    const float* bo     = (const float*)d_in[15];
    const float* ln_f_g = (const float*)d_in[16];
    const float* ln_f_b = (const float*)d_in[17];
    const float* W_ff1  = (const float*)d_in[18];
    const float* b_ff1  = (const float*)d_in[19];
    const float* W_ff2  = (const float*)d_in[20];
    const float* b_ff2  = (const float*)d_in[21];
    (void)in_sizes; (void)n_in; (void)out_size; (void)ws_size;

    char* ws = (char*)d_ws;
    const size_t MB = 1u << 20;
    int*    idx    = (int*)ws;                        // 1 MB
    ushort* xb     = (ushort*)(ws + 1 * MB);          // 8 MB  (LN out; reused as h)
    ushort* qkvw   = (ushort*)(ws + 9 * MB);          // 32 MB [16384][1024]; feats1 overlays
    ushort* ff1b   = (ushort*)(ws + 41 * MB);         // 32 MB (ff1 out)
    ushort* ab     = (ushort*)(ws + 73 * MB);         // 16 MB [16384][512]
    ushort* BtQKVW = (ushort*)(ws + 89 * MB);         // [1024][256] = 512 KB
    ushort* WoT    = BtQKVW + 262144;                 // 128 KB
    ushort* Wf1T   = WoT + 65536;                     // [1024][256] 512 KB
    ushort* Wf2T   = Wf1T + 262144;                   // [256][1024] 512 KB
    ushort* Wq_bf  = Wf2T + 262144;                   // 128 KB
    ushort* w2bd   = Wq_bf + 65536;                   // 128 KB
    ushort* BtCat  = w2bd + 65536;                    // [256][512] 256 KB
    float*  bqkvw  = (float*)(BtCat + 131072);        // 1024 f32
    float*  boc    = bqkvw + 1024;                    // 256 f32
    float*  feats1 = (float*)(ws + 9 * MB);           // overlays qkvw (dead by then)
    ushort* hb     = xb;                              // overlays xb (dead by then)

    // ---- weight preprocessing (3 launches) ----
    tconv_all<<<768, 256, 0, stream>>>(Wq, Wk, Wv, Wo, W_ff1, W_ff2,
                                       BtQKVW, WoT, Wf1T, Wf2T);
    prep_mb<<<773, 256, 0, stream>>>(W_rel2, Wq, WoT, bq, bk, bv, bo, b_rel2, Wo,
                                     w2bd, Wq_bf, BtCat, bqkvw, boc);
    gemm_pre2<<<8, 256, 0, stream>>>(w2bd, Wq_bf, WoT, BtQKVW + 768 * 256, BtCat + 256);

    // ---- main pipeline ----
    knn_kernel<<<MTOT / QPB, 256, 0, stream>>>(xyz, idx);
    ln_kernel<<<MTOT / 4, 256, 0, stream>>>(feats, ln_q_g, ln_q_b, xb);

    // fused q|k|v|qw GEMM: [16384][1024]
    gemm_bt<0, 1, 0><<<dim3(8, 128), 256, 0, stream>>>(xb, BtQKVW, bqkvw, nullptr,
                                                       qkvw, MTOT, 1024, 256, 1024);

    attn_kernel<<<MTOT / PTS, 256, 0, stream>>>(idx, qkvw, xyz, W_rel1, b_rel1, ab);

    // feats1 = [partial|hp] @ BtCat^T + boc + feats   (128x64 tiles, 2 blk/CU)
    gemm_n64<<<dim3(4, 128), 256, 0, stream>>>(ab, BtCat, boc, feats, feats1, MTOT, 256, 512, 256);
    ln_kernel<<<MTOT / 4, 256, 0, stream>>>(feats1, ln_f_g, ln_f_b, hb);
    gemm_bt<1, 1, 0><<<dim3(8, 128), 256, 0, stream>>>(hb, Wf1T, b_ff1, nullptr, ff1b, MTOT, 1024, 256, 1024);
    // out = ff1 @ W_ff2 + b_ff2 + feats1   (128x64 tiles)
    gemm_n64<<<dim3(4, 128), 256, 0, stream>>>(ff1b, Wf2T, b_ff2, feats1, (float*)d_out, MTOT, 256, 1024, 256);
}

// Round 19
// 238.709 us; speedup vs baseline: 1.4511x; 1.0072x over previous
//
#include <hip/hip_runtime.h>
#include <hip/hip_bf16.h>
#include <math.h>

#define NB 4
#define NPTS 4096
#define DIM 256
#define KNN 16
#define HID 64
#define FFDIM 1024
#define LN_EPS 1e-5f
#define MTOT (NB * NPTS)
#define KINF 3e38f
#define QPB 8

typedef __attribute__((ext_vector_type(8))) short short8;
typedef __attribute__((ext_vector_type(4))) float f32x4;

__device__ __forceinline__ float gelu_f(float x) {
    return 0.5f * x * (1.0f + erff(x * 0.7071067811865476f));
}
__device__ __forceinline__ float b2f(ushort u) {
    return __uint_as_float(((unsigned)u) << 16);
}
__device__ __forceinline__ ushort f2b(float f) {
    unsigned u = __float_as_uint(f);
    return (ushort)((u + 0x7fffu + ((u >> 16) & 1u)) >> 16);
}
__device__ __forceinline__ void gload16(const void* g, void* l) {
    __builtin_amdgcn_global_load_lds((const __attribute__((address_space(1))) void*)g,
                                     (__attribute__((address_space(3))) void*)l, 16, 0, 0);
}
// dot of 8 bf16 (packed in uint4) with 8 consecutive f32
__device__ __forceinline__ float dot8(uint4 w, const float* q) {
    float s = 0.f;
    s += b2f((ushort)(w.x & 0xffff)) * q[0]; s += b2f((ushort)(w.x >> 16)) * q[1];
    s += b2f((ushort)(w.y & 0xffff)) * q[2]; s += b2f((ushort)(w.y >> 16)) * q[3];
    s += b2f((ushort)(w.z & 0xffff)) * q[4]; s += b2f((ushort)(w.z >> 16)) * q[5];
    s += b2f((ushort)(w.w & 0xffff)) * q[6]; s += b2f((ushort)(w.w >> 16)) * q[7];
    return s;
}

// ---------------------------------------------------------------------------
// KNN v8 (round-13 validated, 68us — FROZEN).
// ---------------------------------------------------------------------------
__global__ __launch_bounds__(256) void knn_kernel(const float* __restrict__ xyz,
                                                  int* __restrict__ idx_out) {
    int blk = blockIdx.x;              // MTOT/QPB = 2048
    int bq0 = blk * QPB;
    int b = bq0 >> 12;
    const float* base = xyz + (size_t)b * NPTS * 3;
    int t = threadIdx.x;
    int lane = t & 63, wv = t >> 6;

    __shared__ float pxS[NPTS];        // 16 KB
    __shared__ float pyS[NPTS];
    __shared__ float pzS[NPTS];
    __shared__ int   cnt[QPB];
    __shared__ float cV[QPB][64];
    __shared__ int   cI[QPB][64];

    if (t < QPB) cnt[t] = 0;
    for (int i = t; i < NPTS; i += 256) {
        pxS[i] = base[i * 3 + 0];
        pyS[i] = base[i * 3 + 1];
        pzS[i] = base[i * 3 + 2];
    }
    __syncthreads();                   // the only barrier

    #pragma unroll 1
    for (int rep = 0; rep < 2; ++rep) {
        int qi = wv + 4 * rep;         // wave-private query slot
        int bn = bq0 + qi;
        int n = bn & (NPTS - 1);
        float qx = pxS[n], qy = pyS[n], qz = pzS[n];
        float sqn = qx * qx + qy * qy + qz * qz;

        float d[64];
        float lm = KINF;
        #pragma unroll
        for (int i = 0; i < 64; ++i) {
            int m = lane + 64 * i;
            float x = pxS[m], y = pyS[m], z = pzS[m];
            float sqm = x * x + y * y + z * z;
            float dot = qx * x + qy * y + qz * z;
            float dd = (sqn + sqm) - 2.0f * dot;
            d[i] = (m == n) ? KINF : dd;
            lm = fminf(lm, d[i]);
        }

        float v = lm;
        #pragma unroll
        for (int k = 2; k <= 64; k <<= 1) {
            #pragma unroll
            for (int j = 32; j > 0; j >>= 1) {
                if (j < k) {
                    float ov = __shfl_xor(v, j, 64);
                    bool keepMin = ((lane & k) == 0) == ((lane & j) == 0);
                    if (keepMin == (ov < v)) v = ov;
                }
            }
        }
        float T = __shfl(v, 15, 64);   // 16th-smallest lane-min

        #pragma unroll
        for (int i = 0; i < 64; ++i) {
            if (d[i] <= T) {
                int pos = atomicAdd(&cnt[qi], 1);
                if (pos < 64) { cV[qi][pos] = d[i]; cI[qi][pos] = lane + 64 * i; }
            }
        }

        int nc = cnt[qi]; nc = nc > 64 ? 64 : nc;
        float v2 = (lane < nc) ? cV[qi][lane] : KINF;
        int   m2 = (lane < nc) ? cI[qi][lane] : 0x7fffffff;
        #pragma unroll
        for (int k = 2; k <= 64; k <<= 1) {
            #pragma unroll
            for (int j = 32; j > 0; j >>= 1) {
                if (j < k) {
                    float ov = __shfl_xor(v2, j, 64);
                    int   om = __shfl_xor(m2, j, 64);
                    bool keepMin = ((lane & k) == 0) == ((lane & j) == 0);
                    bool less = (ov < v2) || (ov == v2 && om < m2);
                    if (keepMin == less) { v2 = ov; m2 = om; }
                }
            }
        }
        if (lane < KNN) idx_out[(size_t)bn * KNN + lane] = m2;
    }
}

// ---------------------------------------------------------------------------
// LayerNorm v2 (validated round 16)
// ---------------------------------------------------------------------------
__global__ __launch_bounds__(256) void ln_kernel(const float* __restrict__ in,
                                                 const float* __restrict__ g,
                                                 const float* __restrict__ bb,
                                                 ushort* __restrict__ out) {
    int lane = threadIdx.x & 63, wv = threadIdx.x >> 6;
    int r = blockIdx.x * 4 + wv;
    const float* row = in + (size_t)r * DIM;

    float4 v = *(const float4*)(row + lane * 4);
    float s = v.x + v.y + v.z + v.w;
    #pragma unroll
    for (int off = 1; off < 64; off <<= 1) s += __shfl_xor(s, off, 64);
    float mean = s * (1.0f / DIM);

    float dx = v.x - mean, dy = v.y - mean, dz = v.z - mean, dw = v.w - mean;
    float s2 = dx * dx + dy * dy + dz * dz + dw * dw;
    #pragma unroll
    for (int off = 1; off < 64; off <<= 1) s2 += __shfl_xor(s2, off, 64);
    float rstd = rsqrtf(s2 * (1.0f / DIM) + LN_EPS);

    float4 gv = *(const float4*)(g + lane * 4);
    float4 bv = *(const float4*)(bb + lane * 4);
    ushort4 o;
    o.x = f2b(dx * rstd * gv.x + bv.x);
    o.y = f2b(dy * rstd * gv.y + bv.y);
    o.z = f2b(dz * rstd * gv.z + bv.z);
    o.w = f2b(dw * rstd * gv.w + bv.w);
    *(ushort4*)(out + (size_t)r * DIM + lane * 4) = o;
}

// ---------------------------------------------------------------------------
// tconv_all (validated round 18)
// ---------------------------------------------------------------------------
__device__ __forceinline__ void ttile(const float* __restrict__ in,
                                      ushort* __restrict__ out, int R, int C,
                                      int r0, int c0, float (*tile)[33]) {
    int tx = threadIdx.x & 31, ty = threadIdx.x >> 5;
    #pragma unroll
    for (int k = 0; k < 4; ++k)
        tile[ty + 8 * k][tx] = in[(size_t)(r0 + ty + 8 * k) * C + c0 + tx];
    __syncthreads();
    #pragma unroll
    for (int k = 0; k < 4; ++k)
        out[(size_t)(c0 + ty + 8 * k) * R + r0 + tx] = f2b(tile[tx][ty + 8 * k]);
}

__global__ __launch_bounds__(256) void tconv_all(
    const float* __restrict__ Wq, const float* __restrict__ Wk,
    const float* __restrict__ Wv, const float* __restrict__ Wo,
    const float* __restrict__ Wff1, const float* __restrict__ Wff2,
    ushort* __restrict__ BtQKVW, ushort* __restrict__ WoT,
    ushort* __restrict__ Wf1T, ushort* __restrict__ Wf2T)
{
    __shared__ float tile[32][33];
    int tid = blockIdx.x;
    if (tid < 256) {
        int m = tid >> 6, local = tid & 63;
        int r0 = (local >> 3) * 32, c0 = (local & 7) * 32;
        const float* in = (m == 0) ? Wq : (m == 1) ? Wk : (m == 2) ? Wv : Wo;
        ushort* out = (m == 3) ? WoT : BtQKVW + m * 65536;
        ttile(in, out, 256, 256, r0, c0, tile);
    } else if (tid < 512) {
        int local = tid - 256;
        int r0 = (local >> 5) * 32, c0 = (local & 31) * 32;
        ttile(Wff1, Wf1T, 256, 1024, r0, c0, tile);
    } else {
        int local = tid - 512;
        int r0 = (local >> 3) * 32, c0 = (local & 7) * 32;
        ttile(Wff2, Wf2T, 1024, 256, r0, c0, tile);
    }
}

// ---------------------------------------------------------------------------
// prep_mb (validated round 18)
// ---------------------------------------------------------------------------
__global__ __launch_bounds__(256) void prep_mb(const float* __restrict__ W2,
                                               const float* __restrict__ Wq,
                                               const ushort* __restrict__ WoT,
                                               const float* __restrict__ bq,
                                               const float* __restrict__ bk,
                                               const float* __restrict__ bv,
                                               const float* __restrict__ bo,
                                               const float* __restrict__ br2,
                                               const float* __restrict__ Wo,
                                               ushort* __restrict__ w2bd,
                                               ushort* __restrict__ Wq_bf,
                                               ushort* __restrict__ BtCat,
                                               float* __restrict__ bqkvw,
                                               float* __restrict__ boc) {
    int bb = blockIdx.x, t = threadIdx.x;
    if (bb < 256) {
        float v = ((t >> 6) == (bb >> 6)) ? W2[(bb & 63) * 256 + t] : 0.0f;
        w2bd[bb * 256 + t] = f2b(v);
    } else if (bb < 512) {
        int r = bb - 256;
        Wq_bf[r * 256 + t] = f2b(Wq[r * 256 + t]);
    } else if (bb < 768) {
        int r = bb - 512;
        BtCat[(size_t)r * 512 + t] = WoT[r * 256 + t];
    } else {
        int pb = bb - 768;
        if (pb == 0) bqkvw[t] = bq[t];
        else if (pb == 1) bqkvw[256 + t] = bk[t];
        else if (pb == 2) bqkvw[512 + t] = bv[t];
        else if (pb == 3) {
            int h = t >> 6, i = t & 63;
            float s = 0.f;
            #pragma unroll 8
            for (int dp = 0; dp < 64; ++dp) s += bq[h * 64 + dp] * W2[i * 256 + h * 64 + dp];
            bqkvw[768 + t] = s;
        } else {
            float s = bo[t];
            #pragma unroll 8
            for (int d = 0; d < 256; ++d) s += br2[d] * Wo[d * 256 + t];
            boc[t] = s;
        }
    }
}

// ---------------------------------------------------------------------------
// MFMA bf16 GEMM 128x128: C[M][ldc] = act(A@Bt^T + bias) (+res)
// ---------------------------------------------------------------------------
template <int ACT, int OUTBF, int RES>
__global__ __launch_bounds__(256) void gemm_bt(
    const ushort* __restrict__ A, const ushort* __restrict__ Bt,
    const float* __restrict__ bias, const float* __restrict__ res,
    void* __restrict__ Cv, int M, int N, int K, int ldc)
{
    __shared__ ushort As[4096];
    __shared__ ushort Bs[4096];
    const int t = threadIdx.x;
    const int wave = t >> 6, lane = t & 63;
    const int m0 = blockIdx.y * 128, n0 = blockIdx.x * 128;
    const int wr = (wave >> 1) * 64, wc = (wave & 1) * 64;

    f32x4 acc[4][4];
    #pragma unroll
    for (int i = 0; i < 4; ++i)
        #pragma unroll
        for (int j = 0; j < 4; ++j) acc[i][j] = {0.f, 0.f, 0.f, 0.f};

    const int rA0 = (wave * 2 + 0) * 16 + (lane >> 2);
    const int rA1 = (wave * 2 + 1) * 16 + (lane >> 2);
    const int u4 = lane & 3;
    const int sw0 = (rA0 + (rA0 >> 2)) & 3;
    const int sw1 = (rA1 + (rA1 >> 2)) & 3;
    char* ldsA0 = (char*)As + (wave * 2 + 0) * 1024 + lane * 16;
    char* ldsA1 = (char*)As + (wave * 2 + 1) * 1024 + lane * 16;
    char* ldsB0 = (char*)Bs + (wave * 2 + 0) * 1024 + lane * 16;
    char* ldsB1 = (char*)Bs + (wave * 2 + 1) * 1024 + lane * 16;
    const size_t aOff0 = (size_t)(m0 + rA0) * K + (size_t)((u4 ^ sw0) * 8);
    const size_t aOff1 = (size_t)(m0 + rA1) * K + (size_t)((u4 ^ sw1) * 8);
    const size_t bOff0 = (size_t)(n0 + rA0) * K + (size_t)((u4 ^ sw0) * 8);
    const size_t bOff1 = (size_t)(n0 + rA1) * K + (size_t)((u4 ^ sw1) * 8);

    const int cl = lane & 15, gq = lane >> 4;

    for (int k0 = 0; k0 < K; k0 += 32) {
        gload16(A + aOff0 + k0, ldsA0);
        gload16(A + aOff1 + k0, ldsA1);
        gload16(Bt + bOff0 + k0, ldsB0);
        gload16(Bt + bOff1 + k0, ldsB1);
        __syncthreads();

        short8 av[4], bv[4];
        #pragma unroll
        for (int mi = 0; mi < 4; ++mi) {
            int row = wr + mi * 16 + cl;
            int s = (row + (row >> 2)) & 3;
            av[mi] = *(const short8*)((const char*)As + row * 64 + ((gq ^ s) << 4));
            int rowb = wc + mi * 16 + cl;
            int sb = (rowb + (rowb >> 2)) & 3;
            bv[mi] = *(const short8*)((const char*)Bs + rowb * 64 + ((gq ^ sb) << 4));
        }
        #pragma unroll
        for (int mi = 0; mi < 4; ++mi)
            #pragma unroll
            for (int ni = 0; ni < 4; ++ni)
                acc[mi][ni] = __builtin_amdgcn_mfma_f32_16x16x32_bf16(av[mi], bv[ni], acc[mi][ni], 0, 0, 0);
        __syncthreads();
    }

    float* Cf = (float*)Cv;
    ushort* Cb = (ushort*)Cv;
    #pragma unroll
    for (int ni = 0; ni < 4; ++ni) {
        int col = n0 + wc + ni * 16 + cl;
        float bvv = bias ? bias[col] : 0.0f;
        #pragma unroll
        for (int mi = 0; mi < 4; ++mi) {
            #pragma unroll
            for (int r = 0; r < 4; ++r) {
                int row = m0 + wr + mi * 16 + gq * 4 + r;
                float v = acc[mi][ni][r] + bvv;
                if (ACT == 1) v = gelu_f(v);
                if (RES) v += res[(size_t)row * N + col];
                if (OUTBF) Cb[(size_t)row * ldc + col] = f2b(v);
                else       Cf[(size_t)row * ldc + col] = v;
            }
        }
    }
}

// ---------------------------------------------------------------------------
// gemm_pre2 (validated round 18)
// ---------------------------------------------------------------------------
__global__ __launch_bounds__(256) void gemm_pre2(
    const ushort* __restrict__ w2bd, const ushort* __restrict__ Wq_bf,
    const ushort* __restrict__ WoT, ushort* __restrict__ outA,
    ushort* __restrict__ outB)
{
    __shared__ ushort As[4096];
    __shared__ ushort Bs[4096];
    int g = blockIdx.x;
    const ushort* A;  const ushort* Bt;  ushort* Cb;  int ldc;
    int bx, by;
    if (g < 4) { A = w2bd; Bt = Wq_bf; Cb = outA; ldc = 256; bx = g & 1; by = g >> 1; }
    else       { A = WoT;  Bt = w2bd;  Cb = outB; ldc = 512; bx = (g - 4) & 1; by = (g - 4) >> 1; }
    const int K = 256;
    const int t = threadIdx.x;
    const int wave = t >> 6, lane = t & 63;
    const int m0 = by * 128, n0 = bx * 128;
    const int wr = (wave >> 1) * 64, wc = (wave & 1) * 64;

    f32x4 acc[4][4];
    #pragma unroll
    for (int i = 0; i < 4; ++i)
        #pragma unroll
        for (int j = 0; j < 4; ++j) acc[i][j] = {0.f, 0.f, 0.f, 0.f};

    const int rA0 = (wave * 2 + 0) * 16 + (lane >> 2);
    const int rA1 = (wave * 2 + 1) * 16 + (lane >> 2);
    const int u4 = lane & 3;
    const int sw0 = (rA0 + (rA0 >> 2)) & 3;
    const int sw1 = (rA1 + (rA1 >> 2)) & 3;
    char* ldsA0 = (char*)As + (wave * 2 + 0) * 1024 + lane * 16;
    char* ldsA1 = (char*)As + (wave * 2 + 1) * 1024 + lane * 16;
    char* ldsB0 = (char*)Bs + (wave * 2 + 0) * 1024 + lane * 16;
    char* ldsB1 = (char*)Bs + (wave * 2 + 1) * 1024 + lane * 16;
    const size_t aOff0 = (size_t)(m0 + rA0) * K + (size_t)((u4 ^ sw0) * 8);
    const size_t aOff1 = (size_t)(m0 + rA1) * K + (size_t)((u4 ^ sw1) * 8);
    const size_t bOff0 = (size_t)(n0 + rA0) * K + (size_t)((u4 ^ sw0) * 8);
    const size_t bOff1 = (size_t)(n0 + rA1) * K + (size_t)((u4 ^ sw1) * 8);
    const int cl = lane & 15, gq = lane >> 4;

    for (int k0 = 0; k0 < K; k0 += 32) {
        gload16(A + aOff0 + k0, ldsA0);
        gload16(A + aOff1 + k0, ldsA1);
        gload16(Bt + bOff0 + k0, ldsB0);
        gload16(Bt + bOff1 + k0, ldsB1);
        __syncthreads();
        short8 av[4], bv[4];
        #pragma unroll
        for (int mi = 0; mi < 4; ++mi) {
            int row = wr + mi * 16 + cl;
            int s = (row + (row >> 2)) & 3;
            av[mi] = *(const short8*)((const char*)As + row * 64 + ((gq ^ s) << 4));
            int rowb = wc + mi * 16 + cl;
            int sb = (rowb + (rowb >> 2)) & 3;
            bv[mi] = *(const short8*)((const char*)Bs + rowb * 64 + ((gq ^ sb) << 4));
        }
        #pragma unroll
        for (int mi = 0; mi < 4; ++mi)
            #pragma unroll
            for (int ni = 0; ni < 4; ++ni)
                acc[mi][ni] = __builtin_amdgcn_mfma_f32_16x16x32_bf16(av[mi], bv[ni], acc[mi][ni], 0, 0, 0);
        __syncthreads();
    }

    #pragma unroll
    for (int ni = 0; ni < 4; ++ni) {
        int col = n0 + wc + ni * 16 + cl;
        #pragma unroll
        for (int mi = 0; mi < 4; ++mi) {
            #pragma unroll
            for (int r = 0; r < 4; ++r) {
                int row = m0 + wr + mi * 16 + gq * 4 + r;
                Cb[(size_t)row * ldc + col] = f2b(acc[mi][ni][r]);
            }
        }
    }
}

// ---------------------------------------------------------------------------
// MFMA bf16 GEMM 128x64 tile (validated round 17).
// ---------------------------------------------------------------------------
__global__ __launch_bounds__(256) void gemm_n64(
    const ushort* __restrict__ A, const ushort* __restrict__ Bt,
    const float* __restrict__ bias, const float* __restrict__ res,
    float* __restrict__ Cf, int M, int N, int K, int ldc)
{
    __shared__ ushort As[4096];   // [128][32]
    __shared__ ushort Bs[2048];   // [64][32]
    const int t = threadIdx.x;
    const int wave = t >> 6, lane = t & 63;
    const int m0 = blockIdx.y * 128, n0 = blockIdx.x * 64;
    const int wr = wave * 32;

    f32x4 acc[2][4];
    #pragma unroll
    for (int i = 0; i < 2; ++i)
        #pragma unroll
        for (int j = 0; j < 4; ++j) acc[i][j] = {0.f, 0.f, 0.f, 0.f};

    const int rA0 = (wave * 2 + 0) * 16 + (lane >> 2);
    const int rA1 = (wave * 2 + 1) * 16 + (lane >> 2);
    const int rB  = wave * 16 + (lane >> 2);
    const int u4 = lane & 3;
    const int sw0 = (rA0 + (rA0 >> 2)) & 3;
    const int sw1 = (rA1 + (rA1 >> 2)) & 3;
    const int swB = (rB + (rB >> 2)) & 3;
    char* ldsA0 = (char*)As + (wave * 2 + 0) * 1024 + lane * 16;
    char* ldsA1 = (char*)As + (wave * 2 + 1) * 1024 + lane * 16;
    char* ldsB  = (char*)Bs + wave * 1024 + lane * 16;
    const size_t aOff0 = (size_t)(m0 + rA0) * K + (size_t)((u4 ^ sw0) * 8);
    const size_t aOff1 = (size_t)(m0 + rA1) * K + (size_t)((u4 ^ sw1) * 8);
    const size_t bOff  = (size_t)(n0 + rB) * K + (size_t)((u4 ^ swB) * 8);

    const int cl = lane & 15, gq = lane >> 4;

    for (int k0 = 0; k0 < K; k0 += 32) {
        gload16(A + aOff0 + k0, ldsA0);
        gload16(A + aOff1 + k0, ldsA1);
        gload16(Bt + bOff + k0, ldsB);
        __syncthreads();

        short8 av[2], bv[4];
        #pragma unroll
        for (int mi = 0; mi < 2; ++mi) {
            int row = wr + mi * 16 + cl;
            int s = (row + (row >> 2)) & 3;
            av[mi] = *(const short8*)((const char*)As + row * 64 + ((gq ^ s) << 4));
        }
        #pragma unroll
        for (int ni = 0; ni < 4; ++ni) {
            int rowb = ni * 16 + cl;
            int sb = (rowb + (rowb >> 2)) & 3;
            bv[ni] = *(const short8*)((const char*)Bs + rowb * 64 + ((gq ^ sb) << 4));
        }
        #pragma unroll
        for (int mi = 0; mi < 2; ++mi)
            #pragma unroll
            for (int ni = 0; ni < 4; ++ni)
                acc[mi][ni] = __builtin_amdgcn_mfma_f32_16x16x32_bf16(av[mi], bv[ni], acc[mi][ni], 0, 0, 0);
        __syncthreads();
    }

    #pragma unroll
    for (int ni = 0; ni < 4; ++ni) {
        int col = n0 + ni * 16 + cl;
        float bvv = bias[col];
        #pragma unroll
        for (int mi = 0; mi < 2; ++mi) {
            #pragma unroll
            for (int r = 0; r < 4; ++r) {
                int row = m0 + wr + mi * 16 + gq * 4 + r;
                Cf[(size_t)row * ldc + col] = acc[mi][ni][r] + bvv + res[(size_t)row * N + col];
            }
        }
    }
}

// ---------------------------------------------------------------------------
// Attention v6: ILP-2 over points — pairs share each barrier (12/block vs 24),
// both gather chains interleaved for 2x memory-level parallelism. Per-point
// arithmetic identical to validated v5 => bit-identical output.
// ---------------------------------------------------------------------------
#define PTS 8
__global__ __launch_bounds__(256) void attn_kernel(
    const int* __restrict__ idx,
    const ushort* __restrict__ qkvw,
    const float* __restrict__ xyz,
    const float* __restrict__ W1,
    const float* __restrict__ b1,
    ushort* __restrict__ ab)
{
    __shared__ float qS[2][256];
    __shared__ float qwS[2][256];
    __shared__ float psS[2][64];
    __shared__ uint4 hidS4[2][16 * 9];   // [16 rows][stride 144B] each
    __shared__ int   nbAll[128];
    __shared__ float w1S[256];
    __shared__ float b1S[64];

    const int t = threadIdx.x;
    const int h = t >> 6, lane = t & 63;
    const int bid = blockIdx.x;
    const int blk = ((bid & 7) << 8) | (bid >> 3);   // XCD-contiguous, bijective
    const int bn0 = blk * PTS;
    const int R0 = blk * (PTS * 16);

    if (t < 128) nbAll[t] = idx[R0 + t];
    w1S[t] = W1[t];
    if (t < 64) b1S[t] = b1[t];
    const float* xb3 = xyz + (size_t)(bn0 >> 12) * NPTS * 3;
    __syncthreads();   // nbAll/w1S/b1S read cross-wave below

    #pragma unroll 1
    for (int pp = 0; pp < PTS; pp += 2) {
        const int bnA = bn0 + pp;
        const int bnB = bn0 + pp + 1;
        const size_t base = (size_t)(bnA >> 12) * NPTS;

        qS[0][t]  = b2f(qkvw[(size_t)bnA * 1024 + t]);
        qS[1][t]  = b2f(qkvw[(size_t)bnB * 1024 + t]);
        qwS[0][t] = b2f(qkvw[(size_t)bnA * 1024 + 768 + t]);
        qwS[1][t] = b2f(qkvw[(size_t)bnB * 1024 + 768 + t]);
        // hid rows for both points: j = t>>4 (16 rows), 4 dims/thread each
        {
            int j = t >> 4;
            int i0 = (t & 15) * 4;
            int nA = bnA & (NPTS - 1), nB = bnB & (NPTS - 1);
            float nAx = xb3[nA * 3 + 0], nAy = xb3[nA * 3 + 1], nAz = xb3[nA * 3 + 2];
            float nBx = xb3[nB * 3 + 0], nBy = xb3[nB * 3 + 1], nBz = xb3[nB * 3 + 2];
            int mA = nbAll[pp * 16 + j];
            int mB = nbAll[(pp + 1) * 16 + j];
            float dAx = xb3[mA * 3 + 0] - nAx, dAy = xb3[mA * 3 + 1] - nAy, dAz = xb3[mA * 3 + 2] - nAz;
            float dBx = xb3[mB * 3 + 0] - nBx, dBy = xb3[mB * 3 + 1] - nBy, dBz = xb3[mB * 3 + 2] - nBz;
            float nrA = sqrtf(dAx * dAx + dAy * dAy + dAz * dAz);
            float nrB = sqrtf(dBx * dBx + dBy * dBy + dBz * dBz);
            uint2 hwA, hwB;
            float a0, a1;
            a0 = b1S[i0 + 0] + dAx * w1S[i0 + 0] + dAy * w1S[64 + i0 + 0] + dAz * w1S[128 + i0 + 0] + nrA * w1S[192 + i0 + 0];
            a1 = b1S[i0 + 1] + dAx * w1S[i0 + 1] + dAy * w1S[64 + i0 + 1] + dAz * w1S[128 + i0 + 1] + nrA * w1S[192 + i0 + 1];
            hwA.x = (uint)f2b(gelu_f(a0)) | ((uint)f2b(gelu_f(a1)) << 16);
            a0 = b1S[i0 + 2] + dAx * w1S[i0 + 2] + dAy * w1S[64 + i0 + 2] + dAz * w1S[128 + i0 + 2] + nrA * w1S[192 + i0 + 2];
            a1 = b1S[i0 + 3] + dAx * w1S[i0 + 3] + dAy * w1S[64 + i0 + 3] + dAz * w1S[128 + i0 + 3] + nrA * w1S[192 + i0 + 3];
            hwA.y = (uint)f2b(gelu_f(a0)) | ((uint)f2b(gelu_f(a1)) << 16);
            a0 = b1S[i0 + 0] + dBx * w1S[i0 + 0] + dBy * w1S[64 + i0 + 0] + dBz * w1S[128 + i0 + 0] + nrB * w1S[192 + i0 + 0];
            a1 = b1S[i0 + 1] + dBx * w1S[i0 + 1] + dBy * w1S[64 + i0 + 1] + dBz * w1S[128 + i0 + 1] + nrB * w1S[192 + i0 + 1];
            hwB.x = (uint)f2b(gelu_f(a0)) | ((uint)f2b(gelu_f(a1)) << 16);
            a0 = b1S[i0 + 2] + dBx * w1S[i0 + 2] + dBy * w1S[64 + i0 + 2] + dBz * w1S[128 + i0 + 2] + nrB * w1S[192 + i0 + 2];
            a1 = b1S[i0 + 3] + dBx * w1S[i0 + 3] + dBy * w1S[64 + i0 + 3] + dBz * w1S[128 + i0 + 3] + nrB * w1S[192 + i0 + 3];
            hwB.y = (uint)f2b(gelu_f(a0)) | ((uint)f2b(gelu_f(a1)) << 16);
            *(uint2*)((ushort*)hidS4[0] + j * 72 + i0) = hwA;
            *(uint2*)((ushort*)hidS4[1] + j * 72 + i0) = hwB;
        }
        __syncthreads();

        // logits + softmax for both points, interleaved chains
        {
            int j = lane >> 2, sub = lane & 3;
            int mA = nbAll[pp * 16 + j];
            int mB = nbAll[(pp + 1) * 16 + j];
            const ushort* krA = qkvw + (base + mA) * 1024 + 256 + h * 64 + sub * 16;
            const ushort* krB = qkvw + (base + mB) * 1024 + 256 + h * 64 + sub * 16;
            uint4 kaA = *(const uint4*)krA;
            uint4 kaB = *(const uint4*)krB;
            uint4 kcA = *(const uint4*)(krA + 8);
            uint4 kcB = *(const uint4*)(krB + 8);
            const float* qpA = &qS[0][h * 64 + sub * 16];
            const float* qpB = &qS[1][h * 64 + sub * 16];
            float d1A = dot8(kaA, qpA) + dot8(kcA, qpA + 8);
            float d1B = dot8(kaB, qpB) + dot8(kcB, qpB + 8);
            const ushort* hrA = (ushort*)hidS4[0] + j * 72 + sub * 16;
            const ushort* hrB = (ushort*)hidS4[1] + j * 72 + sub * 16;
            uint4 haA = *(const uint4*)hrA;
            uint4 haB = *(const uint4*)hrB;
            uint4 hcA = *(const uint4*)(hrA + 8);
            uint4 hcB = *(const uint4*)(hrB + 8);
            const float* qwA = &qwS[0][h * 64 + sub * 16];
            const float* qwB = &qwS[1][h * 64 + sub * 16];
            float d2A = dot8(haA, qwA) + dot8(hcA, qwA + 8);
            float d2B = dot8(haB, qwB) + dot8(hcB, qwB + 8);
            float pA = d1A + d2A;
            float pB = d1B + d2B;
            pA += __shfl_xor(pA, 1, 64);  pB += __shfl_xor(pB, 1, 64);
            pA += __shfl_xor(pA, 2, 64);  pB += __shfl_xor(pB, 2, 64);
            pA *= 0.125f;                 pB *= 0.125f;
            float mxA = pA, mxB = pB;
            mxA = fmaxf(mxA, __shfl_xor(mxA, 4, 64));  mxB = fmaxf(mxB, __shfl_xor(mxB, 4, 64));
            mxA = fmaxf(mxA, __shfl_xor(mxA, 8, 64));  mxB = fmaxf(mxB, __shfl_xor(mxB, 8, 64));
            mxA = fmaxf(mxA, __shfl_xor(mxA, 16, 64)); mxB = fmaxf(mxB, __shfl_xor(mxB, 16, 64));
            mxA = fmaxf(mxA, __shfl_xor(mxA, 32, 64)); mxB = fmaxf(mxB, __shfl_xor(mxB, 32, 64));
            float eA = expf(pA - mxA), eB = expf(pB - mxB);
            float sA = eA, sB = eB;
            sA += __shfl_xor(sA, 4, 64);  sB += __shfl_xor(sB, 4, 64);
            sA += __shfl_xor(sA, 8, 64);  sB += __shfl_xor(sB, 8, 64);
            sA += __shfl_xor(sA, 16, 64); sB += __shfl_xor(sB, 16, 64);
            sA += __shfl_xor(sA, 32, 64); sB += __shfl_xor(sB, 32, 64);
            float pjA = eA / sA, pjB = eB / sB;
            if (sub == 0) { psS[0][h * 16 + j] = pjA; psS[1][h * 16 + j] = pjB; }
        }
        __syncthreads();

        // partial + hp for both points, interleaved gathers
        {
            float oA = 0.f, hpA = 0.f, oB = 0.f, hpB = 0.f;
            const ushort* hid0 = (ushort*)hidS4[0];
            const ushort* hid1 = (ushort*)hidS4[1];
            #pragma unroll
            for (int j = 0; j < 16; ++j) {
                float pA = psS[0][h * 16 + j];
                float pB = psS[1][h * 16 + j];
                int mA = nbAll[pp * 16 + j];
                int mB = nbAll[(pp + 1) * 16 + j];
                oA  += pA * b2f(qkvw[(base + mA) * 1024 + 512 + t]);
                oB  += pB * b2f(qkvw[(base + mB) * 1024 + 512 + t]);
                hpA += pA * b2f(hid0[j * 72 + lane]);
                hpB += pB * b2f(hid1[j * 72 + lane]);
            }
            ab[(size_t)bnA * 512 + t]       = f2b(oA);
            ab[(size_t)bnA * 512 + 256 + t] = f2b(hpA);
            ab[(size_t)bnB * 512 + t]       = f2b(oB);
            ab[(size_t)bnB * 512 + 256 + t] = f2b(hpB);
        }
        __syncthreads();
    }
}

// ---------------------------------------------------------------------------
extern "C" void kernel_launch(void* const* d_in, const int* in_sizes, int n_in,
                              void* d_out, int out_size, void* d_ws, size_t ws_size,
                              hipStream_t stream) {
    const float* xyz    = (const float*)d_in[0];
    const float* feats  = (const float*)d_in[1];
    const float* ln_q_g = (const float*)d_in[2];
    const float* ln_q_b = (const float*)d_in[3];
    const float* Wq     = (const float*)d_in[4];
    const float* bq     = (const float*)d_in[5];
    const float* Wk     = (const float*)d_in[6];
    const float* bk     = (const float*)d_in[7];
    const float* Wv     = (const float*)d_in[8];
    const float* bv     = (const float*)d_in[9];
    const float* W_rel1 = (const float*)d_in[10];
    const float* b_rel1 = (const float*)d_in[11];
    const float* W_rel2 = (const float*)d_in[12];
    const float* b_rel2 = (const float*)d_in[13];
    const float* Wo     = (const float*)d_in[14];
    const float* bo     = (const float*)d_in[15];
    const float* ln_f_g = (const float*)d_in[16];
    const float* ln_f_b = (const float*)d_in[17];
    const float* W_ff1  = (const float*)d_in[18];
    const float* b_ff1  = (const float*)d_in[19];
    const float* W_ff2  = (const float*)d_in[20];
    const float* b_ff2  = (const float*)d_in[21];
    (void)in_sizes; (void)n_in; (void)out_size; (void)ws_size;

    char* ws = (char*)d_ws;
    const size_t MB = 1u << 20;
    int*    idx    = (int*)ws;                        // 1 MB
    ushort* xb     = (ushort*)(ws + 1 * MB);          // 8 MB  (LN out; reused as h)
    ushort* qkvw   = (ushort*)(ws + 9 * MB);          // 32 MB [16384][1024]; feats1 overlays
    ushort* ff1b   = (ushort*)(ws + 41 * MB);         // 32 MB (ff1 out)
    ushort* ab     = (ushort*)(ws + 73 * MB);         // 16 MB [16384][512]
    ushort* BtQKVW = (ushort*)(ws + 89 * MB);         // [1024][256] = 512 KB
    ushort* WoT    = BtQKVW + 262144;                 // 128 KB
    ushort* Wf1T   = WoT + 65536;                     // [1024][256] 512 KB
    ushort* Wf2T   = Wf1T + 262144;                   // [256][1024] 512 KB
    ushort* Wq_bf  = Wf2T + 262144;                   // 128 KB
    ushort* w2bd   = Wq_bf + 65536;                   // 128 KB
    ushort* BtCat  = w2bd + 65536;                    // [256][512] 256 KB
    float*  bqkvw  = (float*)(BtCat + 131072);        // 1024 f32
    float*  boc    = bqkvw + 1024;                    // 256 f32
    float*  feats1 = (float*)(ws + 9 * MB);           // overlays qkvw (dead by then)
    ushort* hb     = xb;                              // overlays xb (dead by then)

    // ---- weight preprocessing (3 launches) ----
    tconv_all<<<768, 256, 0, stream>>>(Wq, Wk, Wv, Wo, W_ff1, W_ff2,
                                       BtQKVW, WoT, Wf1T, Wf2T);
    prep_mb<<<773, 256, 0, stream>>>(W_rel2, Wq, WoT, bq, bk, bv, bo, b_rel2, Wo,
                                     w2bd, Wq_bf, BtCat, bqkvw, boc);
    gemm_pre2<<<8, 256, 0, stream>>>(w2bd, Wq_bf, WoT, BtQKVW + 768 * 256, BtCat + 256);

    // ---- main pipeline ----
    knn_kernel<<<MTOT / QPB, 256, 0, stream>>>(xyz, idx);
    ln_kernel<<<MTOT / 4, 256, 0, stream>>>(feats, ln_q_g, ln_q_b, xb);

    // fused q|k|v|qw GEMM: [16384][1024]
    gemm_bt<0, 1, 0><<<dim3(8, 128), 256, 0, stream>>>(xb, BtQKVW, bqkvw, nullptr,
                                                       qkvw, MTOT, 1024, 256, 1024);

    attn_kernel<<<MTOT / PTS, 256, 0, stream>>>(idx, qkvw, xyz, W_rel1, b_rel1, ab);

    // feats1 = [partial|hp] @ BtCat^T + boc + feats   (128x64 tiles, 2 blk/CU)
    gemm_n64<<<dim3(4, 128), 256, 0, stream>>>(ab, BtCat, boc, feats, feats1, MTOT, 256, 512, 256);
    ln_kernel<<<MTOT / 4, 256, 0, stream>>>(feats1, ln_f_g, ln_f_b, hb);
    gemm_bt<1, 1, 0><<<dim3(8, 128), 256, 0, stream>>>(hb, Wf1T, b_ff1, nullptr, ff1b, MTOT, 1024, 256, 1024);
    // out = ff1 @ W_ff2 + b_ff2 + feats1   (128x64 tiles)
    gemm_n64<<<dim3(4, 128), 256, 0, stream>>>(ff1b, Wf2T, b_ff2, feats1, (float*)d_out, MTOT, 256, 1024, 256);
}